// Round 1
// baseline (2131.261 us; speedup 1.0000x reference)
//
#include <hip/hip_runtime.h>

#define EMBED 64

// e[idx] = concat(user, item)[idx]; acc (d_out) = same
__global__ void k_init(const float* __restrict__ u, const float* __restrict__ it,
                       float* __restrict__ e, float* __restrict__ acc,
                       int n_u_elems, int n_total_elems) {
    int idx = blockIdx.x * blockDim.x + threadIdx.x;
    if (idx < n_total_elems) {
        float v = (idx < n_u_elems) ? u[idx] : it[idx - n_u_elems];
        e[idx] = v;
        acc[idx] = v;
    }
}

// one wave (64 lanes) per edge; lane = embedding dim
// enew[row*64+lane] += val * e[col*64+lane]
__global__ void k_spmm(const float* __restrict__ vals, const int* __restrict__ rows,
                       const int* __restrict__ cols, const float* __restrict__ e,
                       float* __restrict__ enew, int n_edges) {
    long long gid = (long long)blockIdx.x * blockDim.x + threadIdx.x;
    int edge = (int)(gid >> 6);
    int lane = (int)(gid & 63);
    if (edge < n_edges) {
        float v = vals[edge];
        int c = cols[edge];
        int r = rows[edge];
        float x = e[(long long)c * EMBED + lane] * v;
        atomicAdd(&enew[(long long)r * EMBED + lane], x);
    }
}

// acc += enew
__global__ void k_add(float* __restrict__ acc, const float* __restrict__ enew, int n) {
    int idx = blockIdx.x * blockDim.x + threadIdx.x;
    if (idx < n) acc[idx] += enew[idx];
}

// out *= 0.25
__global__ void k_scale(float* __restrict__ out, int n) {
    int idx = blockIdx.x * blockDim.x + threadIdx.x;
    if (idx < n) out[idx] *= 0.25f;
}

extern "C" void kernel_launch(void* const* d_in, const int* in_sizes, int n_in,
                              void* d_out, int out_size, void* d_ws, size_t ws_size,
                              hipStream_t stream) {
    const float* user_embeds = (const float*)d_in[0];
    const float* item_embeds = (const float*)d_in[1];
    const float* vals        = (const float*)d_in[2];
    const int*   rows        = (const int*)d_in[3];
    const int*   cols        = (const int*)d_in[4];

    const int n_u_elems = in_sizes[0];           // 50000*64
    const int n_i_elems = in_sizes[1];           // 25000*64
    const int n_total   = n_u_elems + n_i_elems; // 75000*64 == out_size
    const int n_edges   = in_sizes[2];           // 3,200,000

    float* acc  = (float*)d_out;
    float* bufA = (float*)d_ws;
    float* bufB = bufA + n_total;

    const size_t node_bytes = (size_t)n_total * sizeof(float);

    // init: e_cur (bufA) = e0, acc = e0
    {
        int blocks = (n_total + 255) / 256;
        k_init<<<blocks, 256, 0, stream>>>(user_embeds, item_embeds, bufA, acc,
                                           n_u_elems, n_total);
    }

    float* e_cur  = bufA;
    float* e_next = bufB;
    const int N_LAYERS = 3;
    for (int layer = 0; layer < N_LAYERS; ++layer) {
        hipMemsetAsync(e_next, 0, node_bytes, stream);
        long long total_threads = (long long)n_edges * EMBED;
        int blocks = (int)((total_threads + 255) / 256);
        k_spmm<<<blocks, 256, 0, stream>>>(vals, rows, cols, e_cur, e_next, n_edges);
        int ablocks = (n_total + 255) / 256;
        k_add<<<ablocks, 256, 0, stream>>>(acc, e_next, n_total);
        // swap
        float* t = e_cur; e_cur = e_next; e_next = t;
    }

    {
        int blocks = (n_total + 255) / 256;
        k_scale<<<blocks, 256, 0, stream>>>(acc, n_total);
    }
}

// Round 2
// 1081.189 us; speedup vs baseline: 1.9712x; 1.9712x over previous
//
#include <hip/hip_runtime.h>

#define EMBED 64

// ---------- shared init / epilogue kernels ----------

__global__ void k_init(const float* __restrict__ u, const float* __restrict__ it,
                       float* __restrict__ e, float* __restrict__ acc,
                       int n_u_elems, int n_total_elems) {
    int idx = blockIdx.x * blockDim.x + threadIdx.x;
    if (idx < n_total_elems) {
        float v = (idx < n_u_elems) ? u[idx] : it[idx - n_u_elems];
        e[idx] = v;
        acc[idx] = v;
    }
}

__global__ void k_scale(float* __restrict__ out, int n) {
    int idx = blockIdx.x * blockDim.x + threadIdx.x;
    if (idx < n) out[idx] *= 0.25f;
}

// ---------- CSR build ----------

__global__ void k_count(const int* __restrict__ rows, int* __restrict__ deg, int n_edges) {
    int e = blockIdx.x * blockDim.x + threadIdx.x;
    if (e < n_edges) atomicAdd(&deg[rows[e]], 1);
}

// single-block exclusive scan over n entries (n ~ 75000), 1024 threads
__global__ void k_scan(const int* __restrict__ deg, int* __restrict__ row_ptr, int n) {
    __shared__ int buf[1024];
    __shared__ int carry_s;
    int tid = threadIdx.x;
    if (tid == 0) carry_s = 0;
    __syncthreads();
    for (int base = 0; base < n; base += 1024) {
        int i = base + tid;
        int v = (i < n) ? deg[i] : 0;
        buf[tid] = v;
        __syncthreads();
        // Hillis-Steele inclusive scan
        for (int off = 1; off < 1024; off <<= 1) {
            int t = (tid >= off) ? buf[tid - off] : 0;
            __syncthreads();
            buf[tid] += t;
            __syncthreads();
        }
        int incl = buf[tid];
        int c = carry_s;
        if (i < n) row_ptr[i] = c + incl - v;
        __syncthreads();
        if (tid == 0) carry_s = c + buf[1023];
        __syncthreads();
    }
    if (tid == 0) row_ptr[n] = carry_s;
}

__global__ void k_scatter(const int* __restrict__ rows, const int* __restrict__ cols,
                          const float* __restrict__ vals, int* __restrict__ cursor,
                          int* __restrict__ scol, float* __restrict__ sval, int n_edges) {
    int e = blockIdx.x * blockDim.x + threadIdx.x;
    if (e < n_edges) {
        int r = rows[e];
        int pos = atomicAdd(&cursor[r], 1);
        scol[pos] = cols[e];
        sval[pos] = vals[e];
    }
}

// ---------- CSR SpMM: one wave per row, lane = embed dim ----------

__global__ void k_spmm_csr(const int* __restrict__ row_ptr, const int* __restrict__ scol,
                           const float* __restrict__ sval, const float* __restrict__ e,
                           float* __restrict__ enew, float* __restrict__ acc, int n_nodes) {
    int gid = blockIdx.x * blockDim.x + threadIdx.x;
    int row = gid >> 6;
    int lane = gid & 63;
    if (row >= n_nodes) return;
    int beg = row_ptr[row];
    int end = row_ptr[row + 1];
    float s0 = 0.f, s1 = 0.f;
    int j = beg;
    for (; j + 1 < end; j += 2) {
        int   c0 = scol[j],     c1 = scol[j + 1];
        float v0 = sval[j],     v1 = sval[j + 1];
        s0 += v0 * e[(size_t)c0 * EMBED + lane];
        s1 += v1 * e[(size_t)c1 * EMBED + lane];
    }
    if (j < end) {
        s0 += sval[j] * e[(size_t)scol[j] * EMBED + lane];
    }
    float sum = s0 + s1;
    size_t o = (size_t)row * EMBED + lane;
    enew[o] = sum;
    acc[o] += sum;
}

// ---------- fallback (round-0 atomic path) ----------

__global__ void k_spmm_atomic(const float* __restrict__ vals, const int* __restrict__ rows,
                              const int* __restrict__ cols, const float* __restrict__ e,
                              float* __restrict__ enew, int n_edges) {
    long long gid = (long long)blockIdx.x * blockDim.x + threadIdx.x;
    int edge = (int)(gid >> 6);
    int lane = (int)(gid & 63);
    if (edge < n_edges) {
        float v = vals[edge];
        int c = cols[edge];
        int r = rows[edge];
        atomicAdd(&enew[(long long)r * EMBED + lane], e[(long long)c * EMBED + lane] * v);
    }
}

__global__ void k_add(float* __restrict__ acc, const float* __restrict__ enew, int n) {
    int idx = blockIdx.x * blockDim.x + threadIdx.x;
    if (idx < n) acc[idx] += enew[idx];
}

extern "C" void kernel_launch(void* const* d_in, const int* in_sizes, int n_in,
                              void* d_out, int out_size, void* d_ws, size_t ws_size,
                              hipStream_t stream) {
    const float* user_embeds = (const float*)d_in[0];
    const float* item_embeds = (const float*)d_in[1];
    const float* vals        = (const float*)d_in[2];
    const int*   rows        = (const int*)d_in[3];
    const int*   cols        = (const int*)d_in[4];

    const int n_u_elems = in_sizes[0];            // 50000*64
    const int n_i_elems = in_sizes[1];            // 25000*64
    const int n_total   = n_u_elems + n_i_elems;  // 75000*64
    const int n_edges   = in_sizes[2];            // 3,200,000
    const int n_nodes   = n_total / EMBED;        // 75000
    const int N_LAYERS  = 3;

    float* acc = (float*)d_out;

    // workspace layout (floats/ints are both 4 B)
    size_t need = (size_t)(2 * n_total) * 4            // e_cur, e_next
                + (size_t)(2 * n_edges) * 4            // sval, scol
                + (size_t)(2 * n_nodes + 1) * 4;       // row_ptr, cursor
    char* p = (char*)d_ws;
    float* e_cur   = (float*)p;               p += (size_t)n_total * 4;
    float* e_next  = (float*)p;               p += (size_t)n_total * 4;

    {
        int blocks = (n_total + 255) / 256;
        k_init<<<blocks, 256, 0, stream>>>(user_embeds, item_embeds, e_cur, acc,
                                           n_u_elems, n_total);
    }

    if (ws_size >= need) {
        float* sval    = (float*)p;           p += (size_t)n_edges * 4;
        int*   scol    = (int*)p;             p += (size_t)n_edges * 4;
        int*   row_ptr = (int*)p;             p += (size_t)(n_nodes + 1) * 4;
        int*   cursor  = (int*)p;

        // ---- build CSR (once; reused for all 3 layers) ----
        hipMemsetAsync(cursor, 0, (size_t)n_nodes * 4, stream);
        int eblocks = (n_edges + 255) / 256;
        k_count<<<eblocks, 256, 0, stream>>>(rows, cursor, n_edges);
        k_scan<<<1, 1024, 0, stream>>>(cursor, row_ptr, n_nodes);
        hipMemcpyAsync(cursor, row_ptr, (size_t)n_nodes * 4,
                       hipMemcpyDeviceToDevice, stream);
        k_scatter<<<eblocks, 256, 0, stream>>>(rows, cols, vals, cursor, scol, sval, n_edges);

        // ---- 3 propagation layers ----
        int sblocks = (n_nodes * 64 + 255) / 256;
        for (int layer = 0; layer < N_LAYERS; ++layer) {
            k_spmm_csr<<<sblocks, 256, 0, stream>>>(row_ptr, scol, sval, e_cur, e_next,
                                                    acc, n_nodes);
            float* t = e_cur; e_cur = e_next; e_next = t;
        }
    } else {
        // fallback: atomic scatter path
        const size_t node_bytes = (size_t)n_total * 4;
        for (int layer = 0; layer < N_LAYERS; ++layer) {
            hipMemsetAsync(e_next, 0, node_bytes, stream);
            long long total_threads = (long long)n_edges * EMBED;
            int blocks = (int)((total_threads + 255) / 256);
            k_spmm_atomic<<<blocks, 256, 0, stream>>>(vals, rows, cols, e_cur, e_next, n_edges);
            int ablocks = (n_total + 255) / 256;
            k_add<<<ablocks, 256, 0, stream>>>(acc, e_next, n_total);
            float* t = e_cur; e_cur = e_next; e_next = t;
        }
    }

    {
        int blocks = (n_total + 255) / 256;
        k_scale<<<blocks, 256, 0, stream>>>(acc, n_total);
    }
}

// Round 3
// 567.383 us; speedup vs baseline: 3.7563x; 1.9056x over previous
//
#include <hip/hip_runtime.h>

#define EMBED 64

// acc = 0.25*e0 ; e_cur = e0   (joint node layout: users then items)
__global__ void k_init(const float* __restrict__ u, const float* __restrict__ it,
                       float* __restrict__ e, float* __restrict__ acc,
                       int n_u_elems, int n_total_elems) {
    int idx = blockIdx.x * blockDim.x + threadIdx.x;
    if (idx < n_total_elems) {
        float v = (idx < n_u_elems) ? u[idx] : it[idx - n_u_elems];
        e[idx] = v;
        acc[idx] = 0.25f * v;
    }
}

// user row_ptr via binary search on the (sorted) first half of rows
__global__ void k_rpu(const int* __restrict__ rows, int* __restrict__ rpu,
                      int n_users, int half) {
    int r = blockIdx.x * blockDim.x + threadIdx.x;
    if (r > n_users) return;
    int lo = 0, hi = half;
    while (lo < hi) {
        int mid = (lo + hi) >> 1;
        if (rows[mid] < r) lo = mid + 1; else hi = mid;
    }
    rpu[r] = lo;
}

// histogram of item rows over the second half of the edge list
__global__ void k_hist(const int* __restrict__ rows_hi, int* __restrict__ cnt,
                       int n_users, int half) {
    int e = blockIdx.x * blockDim.x + threadIdx.x;
    if (e < half) atomicAdd(&cnt[rows_hi[e] - n_users], 1);
}

// 3-phase exclusive scan over n (<=26k) entries, single block of 1024
__global__ void k_scan(const int* __restrict__ cnt, int* __restrict__ rpi, int n) {
    __shared__ int sums[1024];
    int tid = threadIdx.x;
    int CH = (n + 1023) / 1024;
    int beg = tid * CH;
    int end = beg + CH; if (end > n) end = n;
    int s = 0;
    for (int i = beg; i < end; ++i) s += cnt[i];
    sums[tid] = s;
    __syncthreads();
    for (int off = 1; off < 1024; off <<= 1) {
        int t = (tid >= off) ? sums[tid - off] : 0;
        __syncthreads();
        sums[tid] += t;
        __syncthreads();
    }
    int pre = sums[tid] - s;  // exclusive prefix of this thread's chunk
    for (int i = beg; i < end; ++i) {
        int c = cnt[i];
        rpi[i] = pre;
        pre += c;
    }
    if (tid == 1023) rpi[n] = pre;
}

// scatter item-half edges into packed (col,val) 8B records
__global__ void k_scatter(const int* __restrict__ rows_hi, const int* __restrict__ cols_hi,
                          const float* __restrict__ vals_hi, int* __restrict__ cursor,
                          int2* __restrict__ packed, int n_users, int half) {
    int e = blockIdx.x * blockDim.x + threadIdx.x;
    if (e < half) {
        int r = rows_hi[e] - n_users;
        int pos = atomicAdd(&cursor[r], 1);
        packed[pos] = make_int2(cols_hi[e], __float_as_int(vals_hi[e]));
    }
}

// one wave per row, lane = embed dim; user rows pull from in-place CSR,
// item rows pull from packed CSR. acc += 0.25*sum fused; enew store optional.
__global__ void k_spmm(const int* __restrict__ rpu, const int* __restrict__ cols,
                       const float* __restrict__ vals,
                       const int* __restrict__ rpi, const int2* __restrict__ packed,
                       const float* __restrict__ e, float* __restrict__ enew,
                       float* __restrict__ acc, int n_users, int n_nodes,
                       int write_enew) {
    int gid = blockIdx.x * blockDim.x + threadIdx.x;
    int row = gid >> 6;
    int lane = gid & 63;
    if (row >= n_nodes) return;
    float s0 = 0.f, s1 = 0.f, s2 = 0.f, s3 = 0.f;
    if (row < n_users) {
        int beg = rpu[row], end = rpu[row + 1];
        int j = beg;
        for (; j + 3 < end; j += 4) {
            int   c0 = cols[j], c1 = cols[j + 1], c2 = cols[j + 2], c3 = cols[j + 3];
            float v0 = vals[j], v1 = vals[j + 1], v2 = vals[j + 2], v3 = vals[j + 3];
            s0 += v0 * e[(size_t)c0 * EMBED + lane];
            s1 += v1 * e[(size_t)c1 * EMBED + lane];
            s2 += v2 * e[(size_t)c2 * EMBED + lane];
            s3 += v3 * e[(size_t)c3 * EMBED + lane];
        }
        for (; j < end; ++j)
            s0 += vals[j] * e[(size_t)cols[j] * EMBED + lane];
    } else {
        int ir = row - n_users;
        int beg = rpi[ir], end = rpi[ir + 1];
        int j = beg;
        for (; j + 3 < end; j += 4) {
            int2 p0 = packed[j], p1 = packed[j + 1], p2 = packed[j + 2], p3 = packed[j + 3];
            s0 += __int_as_float(p0.y) * e[(size_t)p0.x * EMBED + lane];
            s1 += __int_as_float(p1.y) * e[(size_t)p1.x * EMBED + lane];
            s2 += __int_as_float(p2.y) * e[(size_t)p2.x * EMBED + lane];
            s3 += __int_as_float(p3.y) * e[(size_t)p3.x * EMBED + lane];
        }
        for (; j < end; ++j) {
            int2 p = packed[j];
            s0 += __int_as_float(p.y) * e[(size_t)p.x * EMBED + lane];
        }
    }
    float sum = (s0 + s1) + (s2 + s3);
    size_t o = (size_t)row * EMBED + lane;
    if (write_enew) enew[o] = sum;
    acc[o] += 0.25f * sum;
}

extern "C" void kernel_launch(void* const* d_in, const int* in_sizes, int n_in,
                              void* d_out, int out_size, void* d_ws, size_t ws_size,
                              hipStream_t stream) {
    const float* user_embeds = (const float*)d_in[0];
    const float* item_embeds = (const float*)d_in[1];
    const float* vals        = (const float*)d_in[2];
    const int*   rows        = (const int*)d_in[3];
    const int*   cols        = (const int*)d_in[4];

    const int n_u_elems = in_sizes[0];            // 50000*64
    const int n_i_elems = in_sizes[1];            // 25000*64
    const int n_total   = n_u_elems + n_i_elems;  // 75000*64
    const int n_edges   = in_sizes[2];            // 3,200,000
    const int half      = n_edges / 2;            // 1,600,000 (user-sorted half)
    const int n_users   = n_u_elems / EMBED;      // 50000
    const int n_nodes   = n_total / EMBED;        // 75000
    const int n_items   = n_nodes - n_users;      // 25000
    const int N_LAYERS  = 3;

    float* acc = (float*)d_out;

    char* p = (char*)d_ws;
    float* e_cur  = (float*)p;   p += (size_t)n_total * 4;
    float* e_next = (float*)p;   p += (size_t)n_total * 4;
    int2*  packed = (int2*)p;    p += (size_t)half * 8;
    int*   rpu    = (int*)p;     p += (size_t)(n_users + 1) * 4;
    int*   rpi    = (int*)p;     p += (size_t)(n_items + 1) * 4;
    int*   cnt    = (int*)p;     p += (size_t)n_items * 4;
    int*   cursor = (int*)p;

    // ---- init embeddings + acc ----
    {
        int blocks = (n_total + 255) / 256;
        k_init<<<blocks, 256, 0, stream>>>(user_embeds, item_embeds, e_cur, acc,
                                           n_u_elems, n_total);
    }

    // ---- build: user CSR is in-place (rows sorted); item CSR via packed scatter ----
    {
        int ublocks = (n_users + 1 + 255) / 256;
        k_rpu<<<ublocks, 256, 0, stream>>>(rows, rpu, n_users, half);

        hipMemsetAsync(cnt, 0, (size_t)n_items * 4, stream);
        int hblocks = (half + 255) / 256;
        k_hist<<<hblocks, 256, 0, stream>>>(rows + half, cnt, n_users, half);
        k_scan<<<1, 1024, 0, stream>>>(cnt, rpi, n_items);
        hipMemcpyAsync(cursor, rpi, (size_t)n_items * 4, hipMemcpyDeviceToDevice, stream);
        k_scatter<<<hblocks, 256, 0, stream>>>(rows + half, cols + half, vals + half,
                                               cursor, packed, n_users, half);
    }

    // ---- 3 propagation layers, acc += 0.25*e_k fused; last layer skips enew ----
    {
        int sblocks = (n_nodes * EMBED + 255) / 256;
        for (int layer = 0; layer < N_LAYERS; ++layer) {
            int write_enew = (layer != N_LAYERS - 1);
            k_spmm<<<sblocks, 256, 0, stream>>>(rpu, cols, vals, rpi, packed,
                                                e_cur, e_next, acc,
                                                n_users, n_nodes, write_enew);
            float* t = e_cur; e_cur = e_next; e_next = t;
        }
    }
}

// Round 4
// 502.826 us; speedup vs baseline: 4.2386x; 1.1284x over previous
//
#include <hip/hip_runtime.h>

#define EMBED 64

// acc = 0.25*e0 ; e_cur = e0   (float4-vectorized; joint layout users||items)
__global__ void k_init(const float4* __restrict__ u, const float4* __restrict__ it,
                       float4* __restrict__ e, float4* __restrict__ acc,
                       int n_u_vec, int n_total_vec) {
    int idx = blockIdx.x * blockDim.x + threadIdx.x;
    if (idx < n_total_vec) {
        float4 v = (idx < n_u_vec) ? u[idx] : it[idx - n_u_vec];
        e[idx] = v;
        float4 a; a.x = 0.25f * v.x; a.y = 0.25f * v.y; a.z = 0.25f * v.z; a.w = 0.25f * v.w;
        acc[idx] = a;
    }
}

// user row_ptr via binary search on the (sorted) first half of rows
__global__ void k_rpu(const int* __restrict__ rows, int* __restrict__ rp,
                      int n_users, int half) {
    int r = blockIdx.x * blockDim.x + threadIdx.x;
    if (r > n_users) return;
    int lo = 0, hi = half;
    while (lo < hi) {
        int mid = (lo + hi) >> 1;
        if (rows[mid] < r) lo = mid + 1; else hi = mid;
    }
    rp[r] = lo;
}

// histogram of item rows over the second half of the edge list
__global__ void k_hist(const int* __restrict__ rows_hi, int* __restrict__ cnt,
                       int n_users, int half) {
    int e = blockIdx.x * blockDim.x + threadIdx.x;
    if (e < half) atomicAdd(&cnt[rows_hi[e] - n_users], 1);
}

// exclusive scan over n (<=26k) entries; writes rp_items[ir] = base + prefix,
// rp_items[n] = base + total. single block of 1024.
__global__ void k_scan(const int* __restrict__ cnt, int* __restrict__ rp_items,
                       int n, int base) {
    __shared__ int sums[1024];
    int tid = threadIdx.x;
    int CH = (n + 1023) / 1024;
    int beg = tid * CH;
    int end = beg + CH; if (end > n) end = n;
    int s = 0;
    for (int i = beg; i < end; ++i) s += cnt[i];
    sums[tid] = s;
    __syncthreads();
    for (int off = 1; off < 1024; off <<= 1) {
        int t = (tid >= off) ? sums[tid - off] : 0;
        __syncthreads();
        sums[tid] += t;
        __syncthreads();
    }
    int pre = sums[tid] - s;  // exclusive prefix of this thread's chunk
    for (int i = beg; i < end; ++i) {
        int c = cnt[i];
        rp_items[i] = base + pre;
        pre += c;
    }
    if (tid == 1023) rp_items[n] = base + pre;
}

// pack user-half edges in place (rows sorted -> destination == source index)
__global__ void k_pack(const int* __restrict__ cols, const float* __restrict__ vals,
                       int2* __restrict__ packed, int half) {
    int e = blockIdx.x * blockDim.x + threadIdx.x;
    if (e < half) packed[e] = make_int2(cols[e], __float_as_int(vals[e]));
}

// scatter item-half edges into packed (col,val) 8B records (cursor preloaded with rp)
__global__ void k_scatter(const int* __restrict__ rows_hi, const int* __restrict__ cols_hi,
                          const float* __restrict__ vals_hi, int* __restrict__ cursor,
                          int2* __restrict__ packed, int n_users, int half) {
    int e = blockIdx.x * blockDim.x + threadIdx.x;
    if (e < half) {
        int r = rows_hi[e] - n_users;
        int pos = atomicAdd(&cursor[r], 1);
        packed[pos] = make_int2(cols_hi[e], __float_as_int(vals_hi[e]));
    }
}

// one wave per row; lane = 16*grp + sub. group g handles edges beg+g, beg+g+4, ...
// sub indexes float4 quads of the 64-dim row. 8 edges in flight per wave.
__global__ void k_spmm(const int* __restrict__ rp, const int2* __restrict__ packed,
                       const float4* __restrict__ e4, float4* __restrict__ enew,
                       float4* __restrict__ acc, int n_nodes, int write_enew) {
    int gid = blockIdx.x * blockDim.x + threadIdx.x;
    int row = gid >> 6;
    if (row >= n_nodes) return;
    int lane = threadIdx.x & 63;
    int grp  = lane >> 4;   // edge slot 0..3
    int sub  = lane & 15;   // float4 quad of the row

    int beg = rp[row], end = rp[row + 1];
    float4 s0 = make_float4(0.f, 0.f, 0.f, 0.f);
    float4 s1 = make_float4(0.f, 0.f, 0.f, 0.f);

    int j = beg + grp;
    for (; j + 4 < end; j += 8) {
        int2 p0 = packed[j];
        int2 p1 = packed[j + 4];
        float4 g0 = e4[p0.x * 16 + sub];
        float4 g1 = e4[p1.x * 16 + sub];
        float v0 = __int_as_float(p0.y);
        float v1 = __int_as_float(p1.y);
        s0.x += v0 * g0.x; s0.y += v0 * g0.y; s0.z += v0 * g0.z; s0.w += v0 * g0.w;
        s1.x += v1 * g1.x; s1.y += v1 * g1.y; s1.z += v1 * g1.z; s1.w += v1 * g1.w;
    }
    for (; j < end; j += 4) {
        int2 p = packed[j];
        float4 g = e4[p.x * 16 + sub];
        float v = __int_as_float(p.y);
        s0.x += v * g.x; s0.y += v * g.y; s0.z += v * g.z; s0.w += v * g.w;
    }

    float4 s;
    s.x = s0.x + s1.x; s.y = s0.y + s1.y; s.z = s0.z + s1.z; s.w = s0.w + s1.w;
    // reduce across the 4 groups (lanes xor 16, xor 32)
    s.x += __shfl_xor(s.x, 16, 64); s.y += __shfl_xor(s.y, 16, 64);
    s.z += __shfl_xor(s.z, 16, 64); s.w += __shfl_xor(s.w, 16, 64);
    s.x += __shfl_xor(s.x, 32, 64); s.y += __shfl_xor(s.y, 32, 64);
    s.z += __shfl_xor(s.z, 32, 64); s.w += __shfl_xor(s.w, 32, 64);

    if (grp == 0) {
        int o = row * 16 + sub;
        float4 a = acc[o];
        a.x += 0.25f * s.x; a.y += 0.25f * s.y; a.z += 0.25f * s.z; a.w += 0.25f * s.w;
        acc[o] = a;
        if (write_enew) enew[o] = s;
    }
}

extern "C" void kernel_launch(void* const* d_in, const int* in_sizes, int n_in,
                              void* d_out, int out_size, void* d_ws, size_t ws_size,
                              hipStream_t stream) {
    const float* user_embeds = (const float*)d_in[0];
    const float* item_embeds = (const float*)d_in[1];
    const float* vals        = (const float*)d_in[2];
    const int*   rows        = (const int*)d_in[3];
    const int*   cols        = (const int*)d_in[4];

    const int n_u_elems = in_sizes[0];            // 50000*64
    const int n_i_elems = in_sizes[1];            // 25000*64
    const int n_total   = n_u_elems + n_i_elems;  // 75000*64
    const int n_edges   = in_sizes[2];            // 3,200,000
    const int half      = n_edges / 2;            // user-sorted half
    const int n_users   = n_u_elems / EMBED;      // 50000
    const int n_nodes   = n_total / EMBED;        // 75000
    const int n_items   = n_nodes - n_users;      // 25000
    const int N_LAYERS  = 3;

    float* acc = (float*)d_out;

    char* p = (char*)d_ws;
    float* e_cur  = (float*)p;   p += (size_t)n_total * 4;
    float* e_next = (float*)p;   p += (size_t)n_total * 4;
    int2*  packed = (int2*)p;    p += (size_t)n_edges * 8;
    int*   rp     = (int*)p;     p += (size_t)(n_nodes + 1) * 4;   // combined row_ptr
    int*   cnt    = (int*)p;     p += (size_t)n_items * 4;
    int*   cursor = (int*)p;

    // ---- init embeddings + acc (float4) ----
    {
        int nvec = n_total / 4;
        int blocks = (nvec + 255) / 256;
        k_init<<<blocks, 256, 0, stream>>>((const float4*)user_embeds,
                                           (const float4*)item_embeds,
                                           (float4*)e_cur, (float4*)acc,
                                           n_u_elems / 4, nvec);
    }

    // ---- build combined CSR over packed[] ----
    {
        int ublocks = (n_users + 1 + 255) / 256;
        k_rpu<<<ublocks, 256, 0, stream>>>(rows, rp, n_users, half);

        hipMemsetAsync(cnt, 0, (size_t)n_items * 4, stream);
        int hblocks = (half + 255) / 256;
        k_hist<<<hblocks, 256, 0, stream>>>(rows + half, cnt, n_users, half);
        k_scan<<<1, 1024, 0, stream>>>(cnt, rp + n_users, n_items, half);

        k_pack<<<hblocks, 256, 0, stream>>>(cols, vals, packed, half);
        hipMemcpyAsync(cursor, rp + n_users, (size_t)n_items * 4,
                       hipMemcpyDeviceToDevice, stream);
        k_scatter<<<hblocks, 256, 0, stream>>>(rows + half, cols + half, vals + half,
                                               cursor, packed, n_users, half);
    }

    // ---- 3 propagation layers, acc += 0.25*e_k fused; last layer skips enew ----
    {
        int sblocks = (n_nodes * EMBED + 255) / 256;
        for (int layer = 0; layer < N_LAYERS; ++layer) {
            int write_enew = (layer != N_LAYERS - 1);
            k_spmm<<<sblocks, 256, 0, stream>>>(rp, packed,
                                                (const float4*)e_cur, (float4*)e_next,
                                                (float4*)acc, n_nodes, write_enew);
            float* t = e_cur; e_cur = e_next; e_next = t;
        }
    }
}

// Round 5
// 501.662 us; speedup vs baseline: 4.2484x; 1.0023x over previous
//
#include <hip/hip_runtime.h>

#define EMBED 64

// ---------- build kernels ----------

// user row_ptr via binary search on the (sorted) first half of rows
__global__ void k_rpu(const int* __restrict__ rows, int* __restrict__ rp,
                      int n_users, int half) {
    int r = blockIdx.x * blockDim.x + threadIdx.x;
    if (r > n_users) return;
    int lo = 0, hi = half;
    while (lo < hi) {
        int mid = (lo + hi) >> 1;
        if (rows[mid] < r) lo = mid + 1; else hi = mid;
    }
    rp[r] = lo;
}

// histogram of item rows over the second half of the edge list
__global__ void k_hist(const int* __restrict__ rows_hi, int* __restrict__ cnt,
                       int n_users, int half) {
    int e = blockIdx.x * blockDim.x + threadIdx.x;
    if (e < half) atomicAdd(&cnt[rows_hi[e] - n_users], 1);
}

// exclusive scan over n (<=26k) entries; rp_items[i] = base + prefix; rp_items[n]=base+total
__global__ void k_scan(const int* __restrict__ cnt, int* __restrict__ rp_items,
                       int n, int base) {
    __shared__ int sums[1024];
    int tid = threadIdx.x;
    int CH = (n + 1023) / 1024;
    int beg = tid * CH;
    int end = beg + CH; if (end > n) end = n;
    int s = 0;
    for (int i = beg; i < end; ++i) s += cnt[i];
    sums[tid] = s;
    __syncthreads();
    for (int off = 1; off < 1024; off <<= 1) {
        int t = (tid >= off) ? sums[tid - off] : 0;
        __syncthreads();
        sums[tid] += t;
        __syncthreads();
    }
    int pre = sums[tid] - s;
    for (int i = beg; i < end; ++i) {
        int c = cnt[i];
        rp_items[i] = base + pre;
        pre += c;
    }
    if (tid == 1023) rp_items[n] = base + pre;
}

// dinv[r] = deg>0 ? deg^-0.5 : 0 ; users from rp diffs, items from cnt
__global__ void k_dinv(const int* __restrict__ rp, const int* __restrict__ cnt,
                       float* __restrict__ dinv, int n_users, int n_nodes) {
    int r = blockIdx.x * blockDim.x + threadIdx.x;
    if (r >= n_nodes) return;
    int deg = (r < n_users) ? (rp[r + 1] - rp[r]) : cnt[r - n_users];
    dinv[r] = (deg > 0) ? (1.0f / sqrtf((float)deg)) : 0.0f;
}

// f_cur = dinv * e0 ; acc = 0.25 * e0   (float4 over joint layout)
__global__ void k_init(const float4* __restrict__ u, const float4* __restrict__ it,
                       const float* __restrict__ dinv,
                       float4* __restrict__ f, float4* __restrict__ acc,
                       int n_u_vec, int n_total_vec) {
    int idx = blockIdx.x * blockDim.x + threadIdx.x;
    if (idx >= n_total_vec) return;
    float4 v = (idx < n_u_vec) ? u[idx] : it[idx - n_u_vec];
    float dv = dinv[idx >> 4];   // 16 float4 per 64-dim row
    float4 fv; fv.x = dv * v.x; fv.y = dv * v.y; fv.z = dv * v.z; fv.w = dv * v.w;
    float4 a;  a.x = 0.25f * v.x; a.y = 0.25f * v.y; a.z = 0.25f * v.z; a.w = 0.25f * v.w;
    f[idx] = fv;
    acc[idx] = a;
}

// user-half cols -> u16 local item ids, sequential (destination == source index)
__global__ void k_pack16u(const int* __restrict__ cols, unsigned short* __restrict__ col16,
                          int n_users, int half) {
    int e = blockIdx.x * blockDim.x + threadIdx.x;
    if (e < half) col16[e] = (unsigned short)(cols[e] - n_users);
}

// scatter item-half cols (user ids < 50000 -> u16) via per-item cursor
__global__ void k_scatter16(const int* __restrict__ rows_hi, const int* __restrict__ cols_hi,
                            int* __restrict__ cursor, unsigned short* __restrict__ col16,
                            int n_users, int half) {
    int e = blockIdx.x * blockDim.x + threadIdx.x;
    if (e < half) {
        int r = rows_hi[e] - n_users;
        int pos = atomicAdd(&cursor[r], 1);
        col16[pos] = (unsigned short)cols_hi[e];
    }
}

// ---------- SpMM: one wave per row; lane = 16*grp + sub ----------
// S[r] = sum_{c in adj(r)} f[c]  (unweighted);  acc += 0.25*dinv[r]*S ; f_next = dinv[r]^2*S
__global__ void k_spmm(const int* __restrict__ rp, const unsigned short* __restrict__ col16,
                       const float* __restrict__ dinv,
                       const float4* __restrict__ f4, float4* __restrict__ fnext,
                       float4* __restrict__ acc, int n_users, int n_nodes, int write_f) {
    int gid = blockIdx.x * blockDim.x + threadIdx.x;
    int row = gid >> 6;
    if (row >= n_nodes) return;
    int lane = threadIdx.x & 63;
    int grp  = lane >> 4;   // edge slot 0..3
    int sub  = lane & 15;   // float4 quad of the 64-dim row

    int beg = rp[row], end = rp[row + 1];
    int gbase = (row < n_users) ? n_users : 0;   // u16 local -> global node id

    float4 s0 = make_float4(0.f, 0.f, 0.f, 0.f);
    float4 s1 = make_float4(0.f, 0.f, 0.f, 0.f);
    float4 s2 = make_float4(0.f, 0.f, 0.f, 0.f);
    float4 s3 = make_float4(0.f, 0.f, 0.f, 0.f);

    int j = beg + grp;
    // 16 edges in flight per wave
    for (; j + 12 < end; j += 16) {
        int c0 = col16[j];
        int c1 = col16[j + 4];
        int c2 = col16[j + 8];
        int c3 = col16[j + 12];
        float4 g0 = f4[(size_t)(c0 + gbase) * 16 + sub];
        float4 g1 = f4[(size_t)(c1 + gbase) * 16 + sub];
        float4 g2 = f4[(size_t)(c2 + gbase) * 16 + sub];
        float4 g3 = f4[(size_t)(c3 + gbase) * 16 + sub];
        s0.x += g0.x; s0.y += g0.y; s0.z += g0.z; s0.w += g0.w;
        s1.x += g1.x; s1.y += g1.y; s1.z += g1.z; s1.w += g1.w;
        s2.x += g2.x; s2.y += g2.y; s2.z += g2.z; s2.w += g2.w;
        s3.x += g3.x; s3.y += g3.y; s3.z += g3.z; s3.w += g3.w;
    }
    for (; j < end; j += 4) {
        float4 g = f4[(size_t)(col16[j] + gbase) * 16 + sub];
        s0.x += g.x; s0.y += g.y; s0.z += g.z; s0.w += g.w;
    }

    float4 s;
    s.x = (s0.x + s1.x) + (s2.x + s3.x);
    s.y = (s0.y + s1.y) + (s2.y + s3.y);
    s.z = (s0.z + s1.z) + (s2.z + s3.z);
    s.w = (s0.w + s1.w) + (s2.w + s3.w);
    s.x += __shfl_xor(s.x, 16, 64); s.y += __shfl_xor(s.y, 16, 64);
    s.z += __shfl_xor(s.z, 16, 64); s.w += __shfl_xor(s.w, 16, 64);
    s.x += __shfl_xor(s.x, 32, 64); s.y += __shfl_xor(s.y, 32, 64);
    s.z += __shfl_xor(s.z, 32, 64); s.w += __shfl_xor(s.w, 32, 64);

    if (grp == 0) {
        float dv = dinv[row];
        float q  = 0.25f * dv;   // acc weight
        float d2 = dv * dv;      // f_next weight
        int o = row * 16 + sub;
        float4 a = acc[o];
        a.x += q * s.x; a.y += q * s.y; a.z += q * s.z; a.w += q * s.w;
        acc[o] = a;
        if (write_f) {
            float4 fn; fn.x = d2 * s.x; fn.y = d2 * s.y; fn.z = d2 * s.z; fn.w = d2 * s.w;
            fnext[o] = fn;
        }
    }
}

extern "C" void kernel_launch(void* const* d_in, const int* in_sizes, int n_in,
                              void* d_out, int out_size, void* d_ws, size_t ws_size,
                              hipStream_t stream) {
    const float* user_embeds = (const float*)d_in[0];
    const float* item_embeds = (const float*)d_in[1];
    // vals (d_in[2]) no longer needed: folded into dinv
    const int*   rows        = (const int*)d_in[3];
    const int*   cols        = (const int*)d_in[4];

    const int n_u_elems = in_sizes[0];            // 50000*64
    const int n_i_elems = in_sizes[1];            // 25000*64
    const int n_total   = n_u_elems + n_i_elems;  // 75000*64
    const int n_edges   = in_sizes[2];            // 3,200,000
    const int half      = n_edges / 2;            // user-sorted half
    const int n_users   = n_u_elems / EMBED;      // 50000
    const int n_nodes   = n_total / EMBED;        // 75000
    const int n_items   = n_nodes - n_users;      // 25000
    const int N_LAYERS  = 3;

    float* acc = (float*)d_out;

    char* p = (char*)d_ws;
    float* f_cur  = (float*)p;            p += (size_t)n_total * 4;
    float* f_next = (float*)p;            p += (size_t)n_total * 4;
    unsigned short* col16 = (unsigned short*)p;  p += (size_t)n_edges * 2;
    int*   rp     = (int*)p;              p += (size_t)(n_nodes + 1) * 4;
    int*   cnt    = (int*)p;              p += (size_t)n_items * 4;
    int*   cursor = (int*)p;              p += (size_t)n_items * 4;
    float* dinv   = (float*)p;

    // ---- build row pointers + degrees ----
    {
        int ublocks = (n_users + 1 + 255) / 256;
        k_rpu<<<ublocks, 256, 0, stream>>>(rows, rp, n_users, half);

        hipMemsetAsync(cnt, 0, (size_t)n_items * 4, stream);
        int hblocks = (half + 255) / 256;
        k_hist<<<hblocks, 256, 0, stream>>>(rows + half, cnt, n_users, half);
        k_scan<<<1, 1024, 0, stream>>>(cnt, rp + n_users, n_items, half);

        int nblocks = (n_nodes + 255) / 256;
        k_dinv<<<nblocks, 256, 0, stream>>>(rp, cnt, dinv, n_users, n_nodes);
    }

    // ---- init f_cur = dinv*e0, acc = 0.25*e0 ----
    {
        int nvec = n_total / 4;
        int blocks = (nvec + 255) / 256;
        k_init<<<blocks, 256, 0, stream>>>((const float4*)user_embeds,
                                           (const float4*)item_embeds, dinv,
                                           (float4*)f_cur, (float4*)acc,
                                           n_u_elems / 4, nvec);
    }

    // ---- build u16 column array: user half sequential, item half scattered ----
    {
        int hblocks = (half + 255) / 256;
        k_pack16u<<<hblocks, 256, 0, stream>>>(cols, col16, n_users, half);
        hipMemcpyAsync(cursor, rp + n_users, (size_t)n_items * 4,
                       hipMemcpyDeviceToDevice, stream);
        k_scatter16<<<hblocks, 256, 0, stream>>>(rows + half, cols + half,
                                                 cursor, col16, n_users, half);
    }

    // ---- 3 propagation layers ----
    {
        int sblocks = (n_nodes * EMBED + 255) / 256;
        for (int layer = 0; layer < N_LAYERS; ++layer) {
            int write_f = (layer != N_LAYERS - 1);
            k_spmm<<<sblocks, 256, 0, stream>>>(rp, col16, dinv,
                                                (const float4*)f_cur, (float4*)f_next,
                                                (float4*)acc, n_users, n_nodes, write_f);
            float* t = f_cur; f_cur = f_next; f_next = t;
        }
    }
}

// Round 6
// 483.698 us; speedup vs baseline: 4.4062x; 1.0371x over previous
//
#include <hip/hip_runtime.h>

#define EMBED 64
#define IPB 128          // items per bucket (shift 7)
#define MAXNB 256        // max buckets (n_items/IPB = 196)
#define NCHUNK 250       // pass-1/2 chunks

// ---------- build kernels ----------

// user row_ptr via binary search on the (sorted) first half of rows
__global__ void k_rpu(const int* __restrict__ rows, int* __restrict__ rp,
                      int n_users, int half) {
    int r = blockIdx.x * blockDim.x + threadIdx.x;
    if (r > n_users) return;
    int lo = 0, hi = half;
    while (lo < hi) {
        int mid = (lo + hi) >> 1;
        if (rows[mid] < r) lo = mid + 1; else hi = mid;
    }
    rp[r] = lo;
}

// per-item histogram of item rows (for rp_items scan + dinv)
__global__ void k_hist(const int* __restrict__ rows_hi, int* __restrict__ cnt,
                       int n_users, int half) {
    int e = blockIdx.x * blockDim.x + threadIdx.x;
    if (e < half) atomicAdd(&cnt[rows_hi[e] - n_users], 1);
}

// exclusive scan over n (<=26k) entries; rp_items[i]=base+prefix; rp_items[n]=base+total
__global__ void k_scan(const int* __restrict__ cnt, int* __restrict__ rp_items,
                       int n, int base) {
    __shared__ int sums[1024];
    int tid = threadIdx.x;
    int CH = (n + 1023) / 1024;
    int beg = tid * CH;
    int end = beg + CH; if (end > n) end = n;
    int s = 0;
    for (int i = beg; i < end; ++i) s += cnt[i];
    sums[tid] = s;
    __syncthreads();
    for (int off = 1; off < 1024; off <<= 1) {
        int t = (tid >= off) ? sums[tid - off] : 0;
        __syncthreads();
        sums[tid] += t;
        __syncthreads();
    }
    int pre = sums[tid] - s;
    for (int i = beg; i < end; ++i) {
        int c = cnt[i];
        rp_items[i] = base + pre;
        pre += c;
    }
    if (tid == 1023) rp_items[n] = base + pre;
}

// dinv[r] = deg>0 ? deg^-0.5 : 0
__global__ void k_dinv(const int* __restrict__ rp, const int* __restrict__ cnt,
                       float* __restrict__ dinv, int n_users, int n_nodes) {
    int r = blockIdx.x * blockDim.x + threadIdx.x;
    if (r >= n_nodes) return;
    int deg = (r < n_users) ? (rp[r + 1] - rp[r]) : cnt[r - n_users];
    dinv[r] = (deg > 0) ? (1.0f / sqrtf((float)deg)) : 0.0f;
}

// f_cur = dinv * e0 ; acc = 0.25 * e0
__global__ void k_init(const float4* __restrict__ u, const float4* __restrict__ it,
                       const float* __restrict__ dinv,
                       float4* __restrict__ f, float4* __restrict__ acc,
                       int n_u_vec, int n_total_vec) {
    int idx = blockIdx.x * blockDim.x + threadIdx.x;
    if (idx >= n_total_vec) return;
    float4 v = (idx < n_u_vec) ? u[idx] : it[idx - n_u_vec];
    float dv = dinv[idx >> 4];
    float4 fv; fv.x = dv * v.x; fv.y = dv * v.y; fv.z = dv * v.z; fv.w = dv * v.w;
    float4 a;  a.x = 0.25f * v.x; a.y = 0.25f * v.y; a.z = 0.25f * v.z; a.w = 0.25f * v.w;
    f[idx] = fv;
    acc[idx] = a;
}

// user-half cols -> u16 local item ids, sequential
__global__ void k_pack16u(const int* __restrict__ cols, unsigned short* __restrict__ col16,
                          int n_users, int half) {
    int e = blockIdx.x * blockDim.x + threadIdx.x;
    if (e < half) col16[e] = (unsigned short)(cols[e] - n_users);
}

// ---------- binned transpose (item half) ----------

// pass 1: per-chunk bucket histogram. h[chunk][nb]
__global__ void k_bhist(const int* __restrict__ rows_hi, int* __restrict__ h,
                        int n_users, int half, int chunk, int nb) {
    __shared__ int lh[MAXNB];
    int b = blockIdx.x;
    int tid = threadIdx.x;
    if (tid < nb) lh[tid] = 0;
    __syncthreads();
    int beg = b * chunk;
    int end = beg + chunk; if (end > half) end = half;
    for (int e = beg + tid; e < end; e += 256)
        atomicAdd(&lh[(rows_hi[e] - n_users) >> 7], 1);
    __syncthreads();
    if (tid < nb) h[(size_t)b * nb + tid] = lh[tid];
}

// offset table: off[bucket][chunk] = bucketBase + running sum of h[.][bucket]
__global__ void k_boff(const int* __restrict__ rp, const int* __restrict__ h,
                       int* __restrict__ off, int n_users, int n_items,
                       int nb, int nchunk) {
    int k = blockIdx.x * blockDim.x + threadIdx.x;
    if (k >= nb) return;
    int first = k * IPB; if (first > n_items) first = n_items;
    int base = rp[n_users + first];           // absolute position in col16
    for (int b = 0; b < nchunk; ++b) {
        off[(size_t)k * nchunk + b] = base;
        base += h[(size_t)b * nb + k];
    }
}

// pass 2: scatter chunk edges into bucket staging via per-block LDS cursors
__global__ void k_bscatter(const int* __restrict__ rows_hi, const int* __restrict__ cols_hi,
                           const int* __restrict__ off, unsigned int* __restrict__ stage,
                           int n_users, int half, int chunk, int nb, int nchunk) {
    __shared__ int cur[MAXNB];
    int b = blockIdx.x;
    int tid = threadIdx.x;
    if (tid < nb) cur[tid] = off[(size_t)tid * nchunk + b];
    __syncthreads();
    int beg = b * chunk;
    int end = beg + chunk; if (end > half) end = half;
    for (int e = beg + tid; e < end; e += 256) {
        int item = rows_hi[e] - n_users;
        int user = cols_hi[e];
        int pos = atomicAdd(&cur[item >> 7], 1);
        stage[pos] = (unsigned int)user | ((unsigned int)item << 16);
    }
}

// pass 3: one block per bucket; rank staged edges into final per-item positions
__global__ void k_brank(const int* __restrict__ rp, const unsigned int* __restrict__ stage,
                        unsigned short* __restrict__ col16, int n_users, int n_items) {
    __shared__ int cur[IPB];
    int k = blockIdx.x;
    int tid = threadIdx.x;
    int first = k * IPB; if (first > n_items) first = n_items;
    int last = first + IPB; if (last > n_items) last = n_items;
    int nit = last - first;
    for (int i = tid; i < nit; i += 256) cur[i] = rp[n_users + first + i];
    __syncthreads();
    int beg = rp[n_users + first];
    int end = rp[n_users + last];
    for (int i = beg + tid; i < end; i += 256) {
        unsigned int r = stage[i];
        int il = (int)(r >> 16) - first;
        int pos = atomicAdd(&cur[il], 1);
        col16[pos] = (unsigned short)(r & 0xFFFFu);
    }
}

// ---------- SpMM: one wave per row; lane = 16*grp + sub ----------
__global__ void k_spmm(const int* __restrict__ rp, const unsigned short* __restrict__ col16,
                       const float* __restrict__ dinv,
                       const float4* __restrict__ f4, float4* __restrict__ fnext,
                       float4* __restrict__ acc, int row0, int row1,
                       int gbase, int write_f) {
    int gid = blockIdx.x * blockDim.x + threadIdx.x;
    int row = row0 + (gid >> 6);
    if (row >= row1) return;
    int lane = threadIdx.x & 63;
    int grp  = lane >> 4;
    int sub  = lane & 15;

    int beg = rp[row], end = rp[row + 1];

    float4 s0 = make_float4(0.f, 0.f, 0.f, 0.f);
    float4 s1 = make_float4(0.f, 0.f, 0.f, 0.f);
    float4 s2 = make_float4(0.f, 0.f, 0.f, 0.f);
    float4 s3 = make_float4(0.f, 0.f, 0.f, 0.f);

    int j = beg + grp;
    for (; j + 12 < end; j += 16) {
        int c0 = col16[j];
        int c1 = col16[j + 4];
        int c2 = col16[j + 8];
        int c3 = col16[j + 12];
        float4 g0 = f4[(size_t)(c0 + gbase) * 16 + sub];
        float4 g1 = f4[(size_t)(c1 + gbase) * 16 + sub];
        float4 g2 = f4[(size_t)(c2 + gbase) * 16 + sub];
        float4 g3 = f4[(size_t)(c3 + gbase) * 16 + sub];
        s0.x += g0.x; s0.y += g0.y; s0.z += g0.z; s0.w += g0.w;
        s1.x += g1.x; s1.y += g1.y; s1.z += g1.z; s1.w += g1.w;
        s2.x += g2.x; s2.y += g2.y; s2.z += g2.z; s2.w += g2.w;
        s3.x += g3.x; s3.y += g3.y; s3.z += g3.z; s3.w += g3.w;
    }
    for (; j < end; j += 4) {
        float4 g = f4[(size_t)(col16[j] + gbase) * 16 + sub];
        s0.x += g.x; s0.y += g.y; s0.z += g.z; s0.w += g.w;
    }

    float4 s;
    s.x = (s0.x + s1.x) + (s2.x + s3.x);
    s.y = (s0.y + s1.y) + (s2.y + s3.y);
    s.z = (s0.z + s1.z) + (s2.z + s3.z);
    s.w = (s0.w + s1.w) + (s2.w + s3.w);
    s.x += __shfl_xor(s.x, 16, 64); s.y += __shfl_xor(s.y, 16, 64);
    s.z += __shfl_xor(s.z, 16, 64); s.w += __shfl_xor(s.w, 16, 64);
    s.x += __shfl_xor(s.x, 32, 64); s.y += __shfl_xor(s.y, 32, 64);
    s.z += __shfl_xor(s.z, 32, 64); s.w += __shfl_xor(s.w, 32, 64);

    if (grp == 0) {
        float dv = dinv[row];
        float q  = 0.25f * dv;
        float d2 = dv * dv;
        int o = row * 16 + sub;
        float4 a = acc[o];
        a.x += q * s.x; a.y += q * s.y; a.z += q * s.z; a.w += q * s.w;
        acc[o] = a;
        if (write_f) {
            float4 fn; fn.x = d2 * s.x; fn.y = d2 * s.y; fn.z = d2 * s.z; fn.w = d2 * s.w;
            fnext[o] = fn;
        }
    }
}

extern "C" void kernel_launch(void* const* d_in, const int* in_sizes, int n_in,
                              void* d_out, int out_size, void* d_ws, size_t ws_size,
                              hipStream_t stream) {
    const float* user_embeds = (const float*)d_in[0];
    const float* item_embeds = (const float*)d_in[1];
    const int*   rows        = (const int*)d_in[3];
    const int*   cols        = (const int*)d_in[4];

    const int n_u_elems = in_sizes[0];            // 50000*64
    const int n_i_elems = in_sizes[1];            // 25000*64
    const int n_total   = n_u_elems + n_i_elems;  // 75000*64
    const int n_edges   = in_sizes[2];            // 3,200,000
    const int half      = n_edges / 2;            // user-sorted half
    const int n_users   = n_u_elems / EMBED;      // 50000
    const int n_nodes   = n_total / EMBED;        // 75000
    const int n_items   = n_nodes - n_users;      // 25000
    const int N_LAYERS  = 3;
    const int nb        = (n_items + IPB - 1) / IPB;    // 196
    const int chunk     = (half + NCHUNK - 1) / NCHUNK; // 6400

    float* acc = (float*)d_out;

    char* p = (char*)d_ws;
    float* f_cur  = (float*)p;                   p += (size_t)n_total * 4;
    float* f_next = (float*)p;                   p += (size_t)n_total * 4;
    unsigned short* col16 = (unsigned short*)p;  p += (size_t)n_edges * 2;
    unsigned int* stage   = (unsigned int*)p;    p += (size_t)n_edges * 4;
    int*   rp     = (int*)p;                     p += (size_t)(n_nodes + 1) * 4;
    int*   cnt    = (int*)p;                     p += (size_t)n_items * 4;
    float* dinv   = (float*)p;                   p += (size_t)n_nodes * 4;
    int*   h      = (int*)p;                     p += (size_t)NCHUNK * MAXNB * 4;
    int*   off    = (int*)p;

    // ---- row pointers + degrees + dinv ----
    {
        int ublocks = (n_users + 1 + 255) / 256;
        k_rpu<<<ublocks, 256, 0, stream>>>(rows, rp, n_users, half);

        hipMemsetAsync(cnt, 0, (size_t)n_items * 4, stream);
        int hblocks = (half + 255) / 256;
        k_hist<<<hblocks, 256, 0, stream>>>(rows + half, cnt, n_users, half);
        k_scan<<<1, 1024, 0, stream>>>(cnt, rp + n_users, n_items, half);

        int nblocks = (n_nodes + 255) / 256;
        k_dinv<<<nblocks, 256, 0, stream>>>(rp, cnt, dinv, n_users, n_nodes);
    }

    // ---- init f_cur = dinv*e0, acc = 0.25*e0 ----
    {
        int nvec = n_total / 4;
        int blocks = (nvec + 255) / 256;
        k_init<<<blocks, 256, 0, stream>>>((const float4*)user_embeds,
                                           (const float4*)item_embeds, dinv,
                                           (float4*)f_cur, (float4*)acc,
                                           n_u_elems / 4, nvec);
    }

    // ---- column arrays: user half sequential; item half via binned transpose ----
    {
        int hblocks = (half + 255) / 256;
        k_pack16u<<<hblocks, 256, 0, stream>>>(cols, col16, n_users, half);

        k_bhist<<<NCHUNK, 256, 0, stream>>>(rows + half, h, n_users, half, chunk, nb);
        k_boff<<<1, 256, 0, stream>>>(rp, h, off, n_users, n_items, nb, NCHUNK);
        k_bscatter<<<NCHUNK, 256, 0, stream>>>(rows + half, cols + half, off, stage,
                                               n_users, half, chunk, nb, NCHUNK);
        k_brank<<<nb, 256, 0, stream>>>(rp, stage, col16, n_users, n_items);
    }

    // ---- 3 propagation layers; users phase then items phase ----
    {
        int ublocks = (n_users * EMBED + 255) / 256;
        int iblocks = (n_items * EMBED + 255) / 256;
        for (int layer = 0; layer < N_LAYERS; ++layer) {
            int write_f = (layer != N_LAYERS - 1);
            // user rows gather from item half (gbase = n_users)
            k_spmm<<<ublocks, 256, 0, stream>>>(rp, col16, dinv,
                                                (const float4*)f_cur, (float4*)f_next,
                                                (float4*)acc, 0, n_users, n_users, write_f);
            // item rows gather from user half (gbase = 0)
            k_spmm<<<iblocks, 256, 0, stream>>>(rp, col16, dinv,
                                                (const float4*)f_cur, (float4*)f_next,
                                                (float4*)acc, n_users, n_nodes, 0, write_f);
            float* t = f_cur; f_cur = f_next; f_next = t;
        }
    }
}

// Round 7
// 408.400 us; speedup vs baseline: 5.2186x; 1.1844x over previous
//
#include <hip/hip_runtime.h>

#define EMBED 64
#define IPB 128          // items per bucket (shift 7)
#define MAXNB 256        // max buckets (n_items/IPB = 196)
#define NCHUNK 250       // pass-1/2 chunks

// ---------- build kernels ----------

// user row_ptr via binary search on the (sorted) first half of rows
__global__ void k_rpu(const int* __restrict__ rows, int* __restrict__ rp,
                      int n_users, int half) {
    int r = blockIdx.x * blockDim.x + threadIdx.x;
    if (r > n_users) return;
    int lo = 0, hi = half;
    while (lo < hi) {
        int mid = (lo + hi) >> 1;
        if (rows[mid] < r) lo = mid + 1; else hi = mid;
    }
    rp[r] = lo;
}

// user dinv from rp diffs
__global__ void k_dinvu(const int* __restrict__ rp, float* __restrict__ dinv, int n_users) {
    int r = blockIdx.x * blockDim.x + threadIdx.x;
    if (r >= n_users) return;
    int deg = rp[r + 1] - rp[r];
    dinv[r] = (deg > 0) ? (1.0f / sqrtf((float)deg)) : 0.0f;
}

// f_cur = dinv * e0 ; acc = 0.25 * e0
__global__ void k_init(const float4* __restrict__ u, const float4* __restrict__ it,
                       const float* __restrict__ dinv,
                       float4* __restrict__ f, float4* __restrict__ acc,
                       int n_u_vec, int n_total_vec) {
    int idx = blockIdx.x * blockDim.x + threadIdx.x;
    if (idx >= n_total_vec) return;
    float4 v = (idx < n_u_vec) ? u[idx] : it[idx - n_u_vec];
    float dv = dinv[idx >> 4];
    float4 fv; fv.x = dv * v.x; fv.y = dv * v.y; fv.z = dv * v.z; fv.w = dv * v.w;
    float4 a;  a.x = 0.25f * v.x; a.y = 0.25f * v.y; a.z = 0.25f * v.z; a.w = 0.25f * v.w;
    f[idx] = fv;
    acc[idx] = a;
}

// user-half cols -> u16 local item ids, sequential
__global__ void k_pack16u(const int* __restrict__ cols, unsigned short* __restrict__ col16,
                          int n_users, int half) {
    int e = blockIdx.x * blockDim.x + threadIdx.x;
    if (e < half) col16[e] = (unsigned short)(cols[e] - n_users);
}

// ---------- binned transpose (item half) ----------

// pass 1: per-chunk bucket histogram. h[chunk][nb]
__global__ void k_bhist(const int* __restrict__ rows_hi, int* __restrict__ h,
                        int n_users, int half, int chunk, int nb) {
    __shared__ int lh[MAXNB];
    int b = blockIdx.x;
    int tid = threadIdx.x;
    if (tid < nb) lh[tid] = 0;
    __syncthreads();
    int beg = b * chunk;
    int end = beg + chunk; if (end > half) end = half;
    for (int e = beg + tid; e < end; e += 256)
        atomicAdd(&lh[(rows_hi[e] - n_users) >> 7], 1);
    __syncthreads();
    if (tid < nb) h[(size_t)b * nb + tid] = lh[tid];
}

// offset table + bucket bases from chunk histograms (no rp dependency)
__global__ void k_boff(const int* __restrict__ h, int* __restrict__ off,
                       int* __restrict__ bbase, int half, int nb, int nchunk) {
    __shared__ int sums[256];
    int tid = threadIdx.x;
    int total = 0;
    if (tid < nb)
        for (int b = 0; b < nchunk; ++b) total += h[(size_t)b * nb + tid];
    sums[tid] = total;
    __syncthreads();
    for (int o = 1; o < 256; o <<= 1) {
        int t = (tid >= o) ? sums[tid - o] : 0;
        __syncthreads();
        sums[tid] += t;
        __syncthreads();
    }
    if (tid < nb) {
        int base = half + sums[tid] - total;   // exclusive prefix + item-region offset
        bbase[tid] = base;
        for (int b = 0; b < nchunk; ++b) {
            off[(size_t)tid * nchunk + b] = base;
            base += h[(size_t)b * nb + tid];
        }
        if (tid == nb - 1) bbase[nb] = base;   // == n_edges
    }
}

// pass 2: scatter chunk edges into bucket staging via per-block LDS cursors
__global__ void k_bscatter(const int* __restrict__ rows_hi, const int* __restrict__ cols_hi,
                           const int* __restrict__ off, unsigned int* __restrict__ stage,
                           int n_users, int half, int chunk, int nb, int nchunk) {
    __shared__ int cur[MAXNB];
    int b = blockIdx.x;
    int tid = threadIdx.x;
    if (tid < nb) cur[tid] = off[(size_t)tid * nchunk + b];
    __syncthreads();
    int beg = b * chunk;
    int end = beg + chunk; if (end > half) end = half;
    for (int e = beg + tid; e < end; e += 256) {
        int item = rows_hi[e] - n_users;
        int user = cols_hi[e];
        int pos = atomicAdd(&cur[item >> 7], 1);
        stage[pos] = (unsigned int)user | ((unsigned int)item << 16);
    }
}

// pass 3 (fused): one block per bucket. LDS-histogram its 128 items over the
// staged edges, LDS-scan -> item rp slice + item dinv, then rank into col16.
__global__ void k_brank2(const int* __restrict__ bbase, const unsigned int* __restrict__ stage,
                         unsigned short* __restrict__ col16, int* __restrict__ rp,
                         float* __restrict__ dinv, int n_users, int n_items, int n_edges) {
    __shared__ int hist[IPB];
    __shared__ int scanbuf[IPB];
    __shared__ int cur[IPB];
    int k = blockIdx.x;
    int tid = threadIdx.x;
    int first = k * IPB;
    int nit = n_items - first; if (nit > IPB) nit = IPB;
    int beg = bbase[k], end = bbase[k + 1];
    if (tid < IPB) hist[tid] = 0;
    __syncthreads();
    for (int i = beg + tid; i < end; i += 256)
        atomicAdd(&hist[(int)(stage[i] >> 16) - first], 1);
    __syncthreads();
    if (tid < IPB) scanbuf[tid] = hist[tid];
    __syncthreads();
    for (int o = 1; o < IPB; o <<= 1) {
        int t = (tid < IPB && tid >= o) ? scanbuf[tid - o] : 0;
        __syncthreads();
        if (tid < IPB) scanbuf[tid] += t;
        __syncthreads();
    }
    if (tid < nit) {
        int pos = beg + scanbuf[tid] - hist[tid];
        rp[n_users + first + tid] = pos;
        cur[tid] = pos;
        int deg = hist[tid];
        dinv[n_users + first + tid] = (deg > 0) ? (1.0f / sqrtf((float)deg)) : 0.0f;
    }
    if (k == 0 && tid == 0) rp[n_users + n_items] = n_edges;
    __syncthreads();
    for (int i = beg + tid; i < end; i += 256) {
        unsigned int r = stage[i];
        int il = (int)(r >> 16) - first;
        int pos = atomicAdd(&cur[il], 1);
        col16[pos] = (unsigned short)(r & 0xFFFFu);
    }
}

// ---------- SpMM: one wave per row; lane = 16*grp + sub ----------
__global__ void k_spmm(const int* __restrict__ rp, const unsigned short* __restrict__ col16,
                       const float* __restrict__ dinv,
                       const float4* __restrict__ f4, float4* __restrict__ fnext,
                       float4* __restrict__ acc, int row0, int row1,
                       int gbase, int write_f) {
    int gid = blockIdx.x * blockDim.x + threadIdx.x;
    int row = row0 + (gid >> 6);
    if (row >= row1) return;
    int lane = threadIdx.x & 63;
    int grp  = lane >> 4;
    int sub  = lane & 15;

    int beg = rp[row], end = rp[row + 1];

    float4 s0 = make_float4(0.f, 0.f, 0.f, 0.f);
    float4 s1 = make_float4(0.f, 0.f, 0.f, 0.f);
    float4 s2 = make_float4(0.f, 0.f, 0.f, 0.f);
    float4 s3 = make_float4(0.f, 0.f, 0.f, 0.f);

    int j = beg + grp;
    for (; j + 12 < end; j += 16) {
        int c0 = col16[j];
        int c1 = col16[j + 4];
        int c2 = col16[j + 8];
        int c3 = col16[j + 12];
        float4 g0 = f4[(size_t)(c0 + gbase) * 16 + sub];
        float4 g1 = f4[(size_t)(c1 + gbase) * 16 + sub];
        float4 g2 = f4[(size_t)(c2 + gbase) * 16 + sub];
        float4 g3 = f4[(size_t)(c3 + gbase) * 16 + sub];
        s0.x += g0.x; s0.y += g0.y; s0.z += g0.z; s0.w += g0.w;
        s1.x += g1.x; s1.y += g1.y; s1.z += g1.z; s1.w += g1.w;
        s2.x += g2.x; s2.y += g2.y; s2.z += g2.z; s2.w += g2.w;
        s3.x += g3.x; s3.y += g3.y; s3.z += g3.z; s3.w += g3.w;
    }
    for (; j < end; j += 4) {
        float4 g = f4[(size_t)(col16[j] + gbase) * 16 + sub];
        s0.x += g.x; s0.y += g.y; s0.z += g.z; s0.w += g.w;
    }

    float4 s;
    s.x = (s0.x + s1.x) + (s2.x + s3.x);
    s.y = (s0.y + s1.y) + (s2.y + s3.y);
    s.z = (s0.z + s1.z) + (s2.z + s3.z);
    s.w = (s0.w + s1.w) + (s2.w + s3.w);
    s.x += __shfl_xor(s.x, 16, 64); s.y += __shfl_xor(s.y, 16, 64);
    s.z += __shfl_xor(s.z, 16, 64); s.w += __shfl_xor(s.w, 16, 64);
    s.x += __shfl_xor(s.x, 32, 64); s.y += __shfl_xor(s.y, 32, 64);
    s.z += __shfl_xor(s.z, 32, 64); s.w += __shfl_xor(s.w, 32, 64);

    if (grp == 0) {
        float dv = dinv[row];
        float q  = 0.25f * dv;
        float d2 = dv * dv;
        int o = row * 16 + sub;
        float4 a = acc[o];
        a.x += q * s.x; a.y += q * s.y; a.z += q * s.z; a.w += q * s.w;
        acc[o] = a;
        if (write_f) {
            float4 fn; fn.x = d2 * s.x; fn.y = d2 * s.y; fn.z = d2 * s.z; fn.w = d2 * s.w;
            fnext[o] = fn;
        }
    }
}

extern "C" void kernel_launch(void* const* d_in, const int* in_sizes, int n_in,
                              void* d_out, int out_size, void* d_ws, size_t ws_size,
                              hipStream_t stream) {
    const float* user_embeds = (const float*)d_in[0];
    const float* item_embeds = (const float*)d_in[1];
    const int*   rows        = (const int*)d_in[3];
    const int*   cols        = (const int*)d_in[4];

    const int n_u_elems = in_sizes[0];            // 50000*64
    const int n_i_elems = in_sizes[1];            // 25000*64
    const int n_total   = n_u_elems + n_i_elems;  // 75000*64
    const int n_edges   = in_sizes[2];            // 3,200,000
    const int half      = n_edges / 2;            // user-sorted half
    const int n_users   = n_u_elems / EMBED;      // 50000
    const int n_nodes   = n_total / EMBED;        // 75000
    const int n_items   = n_nodes - n_users;      // 25000
    const int N_LAYERS  = 3;
    const int nb        = (n_items + IPB - 1) / IPB;    // 196
    const int chunk     = (half + NCHUNK - 1) / NCHUNK; // 6400

    float* acc = (float*)d_out;

    char* p = (char*)d_ws;
    float* f_cur  = (float*)p;                   p += (size_t)n_total * 4;
    float* f_next = (float*)p;                   p += (size_t)n_total * 4;
    unsigned short* col16 = (unsigned short*)p;  p += (size_t)n_edges * 2;
    unsigned int* stage   = (unsigned int*)p;    p += (size_t)n_edges * 4;
    int*   rp     = (int*)p;                     p += (size_t)(n_nodes + 1) * 4;
    float* dinv   = (float*)p;                   p += (size_t)n_nodes * 4;
    int*   h      = (int*)p;                     p += (size_t)NCHUNK * MAXNB * 4;
    int*   off    = (int*)p;                     p += (size_t)MAXNB * NCHUNK * 4;
    int*   bbase  = (int*)p;

    // ---- user rp + user dinv ----
    {
        int ublocks = (n_users + 1 + 255) / 256;
        k_rpu<<<ublocks, 256, 0, stream>>>(rows, rp, n_users, half);
        int dblocks = (n_users + 255) / 256;
        k_dinvu<<<dblocks, 256, 0, stream>>>(rp, dinv, n_users);
    }

    // ---- item half: binned transpose (also produces item rp + item dinv) ----
    {
        int hblocks = (half + 255) / 256;
        k_pack16u<<<hblocks, 256, 0, stream>>>(cols, col16, n_users, half);

        k_bhist<<<NCHUNK, 256, 0, stream>>>(rows + half, h, n_users, half, chunk, nb);
        k_boff<<<1, 256, 0, stream>>>(h, off, bbase, half, nb, NCHUNK);
        k_bscatter<<<NCHUNK, 256, 0, stream>>>(rows + half, cols + half, off, stage,
                                               n_users, half, chunk, nb, NCHUNK);
        k_brank2<<<nb, 256, 0, stream>>>(bbase, stage, col16, rp, dinv,
                                         n_users, n_items, n_edges);
    }

    // ---- init f_cur = dinv*e0, acc = 0.25*e0 (needs full dinv) ----
    {
        int nvec = n_total / 4;
        int blocks = (nvec + 255) / 256;
        k_init<<<blocks, 256, 0, stream>>>((const float4*)user_embeds,
                                           (const float4*)item_embeds, dinv,
                                           (float4*)f_cur, (float4*)acc,
                                           n_u_elems / 4, nvec);
    }

    // ---- 3 propagation layers; users phase then items phase ----
    {
        int ublocks = (n_users * EMBED + 255) / 256;
        int iblocks = (n_items * EMBED + 255) / 256;
        for (int layer = 0; layer < N_LAYERS; ++layer) {
            int write_f = (layer != N_LAYERS - 1);
            k_spmm<<<ublocks, 256, 0, stream>>>(rp, col16, dinv,
                                                (const float4*)f_cur, (float4*)f_next,
                                                (float4*)acc, 0, n_users, n_users, write_f);
            k_spmm<<<iblocks, 256, 0, stream>>>(rp, col16, dinv,
                                                (const float4*)f_cur, (float4*)f_next,
                                                (float4*)acc, n_users, n_nodes, 0, write_f);
            float* t = f_cur; f_cur = f_next; f_next = t;
        }
    }
}

// Round 8
// 330.015 us; speedup vs baseline: 6.4581x; 1.2375x over previous
//
#include <hip/hip_runtime.h>

#define EMBED 64
#define IPB 128          // items per bucket (shift 7)
#define MAXNB 256        // max buckets (n_items/IPB = 196)
#define NCHUNK 250       // pass-1/2 chunks

// ---------- build kernels ----------

// user row_ptr via binary search on the (sorted) first half of rows
__global__ void k_rpu(const int* __restrict__ rows, int* __restrict__ rp,
                      int n_users, int half) {
    int r = blockIdx.x * blockDim.x + threadIdx.x;
    if (r > n_users) return;
    int lo = 0, hi = half;
    while (lo < hi) {
        int mid = (lo + hi) >> 1;
        if (rows[mid] < r) lo = mid + 1; else hi = mid;
    }
    rp[r] = lo;
}

// user dinv from rp diffs
__global__ void k_dinvu(const int* __restrict__ rp, float* __restrict__ dinv, int n_users) {
    int r = blockIdx.x * blockDim.x + threadIdx.x;
    if (r >= n_users) return;
    int deg = rp[r + 1] - rp[r];
    dinv[r] = (deg > 0) ? (1.0f / sqrtf((float)deg)) : 0.0f;
}

// f_cur = dinv * e0 ; acc = 0.25 * e0
__global__ void k_init(const float4* __restrict__ u, const float4* __restrict__ it,
                       const float* __restrict__ dinv,
                       float4* __restrict__ f, float4* __restrict__ acc,
                       int n_u_vec, int n_total_vec) {
    int idx = blockIdx.x * blockDim.x + threadIdx.x;
    if (idx >= n_total_vec) return;
    float4 v = (idx < n_u_vec) ? u[idx] : it[idx - n_u_vec];
    float dv = dinv[idx >> 4];
    float4 fv; fv.x = dv * v.x; fv.y = dv * v.y; fv.z = dv * v.z; fv.w = dv * v.w;
    float4 a;  a.x = 0.25f * v.x; a.y = 0.25f * v.y; a.z = 0.25f * v.z; a.w = 0.25f * v.w;
    f[idx] = fv;
    acc[idx] = a;
}

// user-half cols -> u16 local item ids, sequential
__global__ void k_pack16u(const int* __restrict__ cols, unsigned short* __restrict__ col16,
                          int n_users, int half) {
    int e = blockIdx.x * blockDim.x + threadIdx.x;
    if (e < half) col16[e] = (unsigned short)(cols[e] - n_users);
}

// ---------- binned transpose (item half) ----------

// pass 1: per-chunk bucket histogram h[chunk][nb]; also accumulate tot[bucket]
__global__ void k_bhist(const int* __restrict__ rows_hi, int* __restrict__ h,
                        int* __restrict__ tot, int n_users, int half, int chunk, int nb) {
    __shared__ int lh[MAXNB];
    int b = blockIdx.x;
    int tid = threadIdx.x;
    if (tid < nb) lh[tid] = 0;
    __syncthreads();
    int beg = b * chunk;
    int end = beg + chunk; if (end > half) end = half;
    for (int e = beg + tid; e < end; e += 256)
        atomicAdd(&lh[(rows_hi[e] - n_users) >> 7], 1);
    __syncthreads();
    if (tid < nb) {
        int c = lh[tid];
        h[(size_t)b * nb + tid] = c;
        if (c) atomicAdd(&tot[tid], c);
    }
}

// scan bucket totals -> bbase (single tiny block)
__global__ void k_bscan(const int* __restrict__ tot, int* __restrict__ bbase,
                        int half, int nb, int n_edges) {
    __shared__ int sums[256];
    int tid = threadIdx.x;
    int v = (tid < nb) ? tot[tid] : 0;
    sums[tid] = v;
    __syncthreads();
    for (int o = 1; o < 256; o <<= 1) {
        int t = (tid >= o) ? sums[tid - o] : 0;
        __syncthreads();
        sums[tid] += t;
        __syncthreads();
    }
    if (tid < nb) bbase[tid] = half + sums[tid] - v;
    if (tid == 0) bbase[nb] = n_edges;
}

// per-bucket chunk-offset table: one block per bucket, LDS scan over 250 chunks
__global__ void k_boff2(const int* __restrict__ h, const int* __restrict__ bbase,
                        int* __restrict__ off, int nb, int nchunk) {
    __shared__ int sums[256];
    int k = blockIdx.x;
    int tid = threadIdx.x;
    int v = (tid < nchunk) ? h[(size_t)tid * nb + k] : 0;
    sums[tid] = v;
    __syncthreads();
    for (int o = 1; o < 256; o <<= 1) {
        int t = (tid >= o) ? sums[tid - o] : 0;
        __syncthreads();
        sums[tid] += t;
        __syncthreads();
    }
    if (tid < nchunk) off[(size_t)k * nchunk + tid] = bbase[k] + sums[tid] - v;
}

// pass 2: scatter chunk edges into bucket staging via per-block LDS cursors
__global__ void k_bscatter(const int* __restrict__ rows_hi, const int* __restrict__ cols_hi,
                           const int* __restrict__ off, unsigned int* __restrict__ stage,
                           int n_users, int half, int chunk, int nb, int nchunk) {
    __shared__ int cur[MAXNB];
    int b = blockIdx.x;
    int tid = threadIdx.x;
    if (tid < nb) cur[tid] = off[(size_t)tid * nchunk + b];
    __syncthreads();
    int beg = b * chunk;
    int end = beg + chunk; if (end > half) end = half;
    for (int e = beg + tid; e < end; e += 256) {
        int item = rows_hi[e] - n_users;
        int user = cols_hi[e];
        int pos = atomicAdd(&cur[item >> 7], 1);
        stage[pos] = (unsigned int)user | ((unsigned int)item << 16);
    }
}

// pass 3 (fused): one block per bucket. LDS-histogram its 128 items over the
// staged edges, LDS-scan -> item rp slice + item dinv, then rank into col16.
__global__ void k_brank2(const int* __restrict__ bbase, const unsigned int* __restrict__ stage,
                         unsigned short* __restrict__ col16, int* __restrict__ rp,
                         float* __restrict__ dinv, int n_users, int n_items, int n_edges) {
    __shared__ int hist[IPB];
    __shared__ int scanbuf[IPB];
    __shared__ int cur[IPB];
    int k = blockIdx.x;
    int tid = threadIdx.x;
    int first = k * IPB;
    int nit = n_items - first; if (nit > IPB) nit = IPB;
    int beg = bbase[k], end = bbase[k + 1];
    if (tid < IPB) hist[tid] = 0;
    __syncthreads();
    for (int i = beg + tid; i < end; i += 256)
        atomicAdd(&hist[(int)(stage[i] >> 16) - first], 1);
    __syncthreads();
    if (tid < IPB) scanbuf[tid] = hist[tid];
    __syncthreads();
    for (int o = 1; o < IPB; o <<= 1) {
        int t = (tid < IPB && tid >= o) ? scanbuf[tid - o] : 0;
        __syncthreads();
        if (tid < IPB) scanbuf[tid] += t;
        __syncthreads();
    }
    if (tid < nit) {
        int pos = beg + scanbuf[tid] - hist[tid];
        rp[n_users + first + tid] = pos;
        cur[tid] = pos;
        int deg = hist[tid];
        dinv[n_users + first + tid] = (deg > 0) ? (1.0f / sqrtf((float)deg)) : 0.0f;
    }
    if (k == 0 && tid == 0) rp[n_users + n_items] = n_edges;
    __syncthreads();
    for (int i = beg + tid; i < end; i += 256) {
        unsigned int r = stage[i];
        int il = (int)(r >> 16) - first;
        int pos = atomicAdd(&cur[il], 1);
        col16[pos] = (unsigned short)(r & 0xFFFFu);
    }
}

// ---------- SpMM: one wave per row; lane = 16*grp + sub ----------
__global__ void k_spmm(const int* __restrict__ rp, const unsigned short* __restrict__ col16,
                       const float* __restrict__ dinv,
                       const float4* __restrict__ f4, float4* __restrict__ fnext,
                       float4* __restrict__ acc, int row0, int row1,
                       int gbase, int write_f) {
    int gid = blockIdx.x * blockDim.x + threadIdx.x;
    int row = row0 + (gid >> 6);
    if (row >= row1) return;
    int lane = threadIdx.x & 63;
    int grp  = lane >> 4;
    int sub  = lane & 15;

    int beg = rp[row], end = rp[row + 1];

    float4 s0 = make_float4(0.f, 0.f, 0.f, 0.f);
    float4 s1 = make_float4(0.f, 0.f, 0.f, 0.f);
    float4 s2 = make_float4(0.f, 0.f, 0.f, 0.f);
    float4 s3 = make_float4(0.f, 0.f, 0.f, 0.f);

    int j = beg + grp;
    for (; j + 12 < end; j += 16) {
        int c0 = col16[j];
        int c1 = col16[j + 4];
        int c2 = col16[j + 8];
        int c3 = col16[j + 12];
        float4 g0 = f4[(size_t)(c0 + gbase) * 16 + sub];
        float4 g1 = f4[(size_t)(c1 + gbase) * 16 + sub];
        float4 g2 = f4[(size_t)(c2 + gbase) * 16 + sub];
        float4 g3 = f4[(size_t)(c3 + gbase) * 16 + sub];
        s0.x += g0.x; s0.y += g0.y; s0.z += g0.z; s0.w += g0.w;
        s1.x += g1.x; s1.y += g1.y; s1.z += g1.z; s1.w += g1.w;
        s2.x += g2.x; s2.y += g2.y; s2.z += g2.z; s2.w += g2.w;
        s3.x += g3.x; s3.y += g3.y; s3.z += g3.z; s3.w += g3.w;
    }
    for (; j < end; j += 4) {
        float4 g = f4[(size_t)(col16[j] + gbase) * 16 + sub];
        s0.x += g.x; s0.y += g.y; s0.z += g.z; s0.w += g.w;
    }

    float4 s;
    s.x = (s0.x + s1.x) + (s2.x + s3.x);
    s.y = (s0.y + s1.y) + (s2.y + s3.y);
    s.z = (s0.z + s1.z) + (s2.z + s3.z);
    s.w = (s0.w + s1.w) + (s2.w + s3.w);
    s.x += __shfl_xor(s.x, 16, 64); s.y += __shfl_xor(s.y, 16, 64);
    s.z += __shfl_xor(s.z, 16, 64); s.w += __shfl_xor(s.w, 16, 64);
    s.x += __shfl_xor(s.x, 32, 64); s.y += __shfl_xor(s.y, 32, 64);
    s.z += __shfl_xor(s.z, 32, 64); s.w += __shfl_xor(s.w, 32, 64);

    if (grp == 0) {
        float dv = dinv[row];
        float q  = 0.25f * dv;
        float d2 = dv * dv;
        int o = row * 16 + sub;
        float4 a = acc[o];
        a.x += q * s.x; a.y += q * s.y; a.z += q * s.z; a.w += q * s.w;
        acc[o] = a;
        if (write_f) {
            float4 fn; fn.x = d2 * s.x; fn.y = d2 * s.y; fn.z = d2 * s.z; fn.w = d2 * s.w;
            fnext[o] = fn;
        }
    }
}

extern "C" void kernel_launch(void* const* d_in, const int* in_sizes, int n_in,
                              void* d_out, int out_size, void* d_ws, size_t ws_size,
                              hipStream_t stream) {
    const float* user_embeds = (const float*)d_in[0];
    const float* item_embeds = (const float*)d_in[1];
    const int*   rows        = (const int*)d_in[3];
    const int*   cols        = (const int*)d_in[4];

    const int n_u_elems = in_sizes[0];            // 50000*64
    const int n_i_elems = in_sizes[1];            // 25000*64
    const int n_total   = n_u_elems + n_i_elems;  // 75000*64
    const int n_edges   = in_sizes[2];            // 3,200,000
    const int half      = n_edges / 2;            // user-sorted half
    const int n_users   = n_u_elems / EMBED;      // 50000
    const int n_nodes   = n_total / EMBED;        // 75000
    const int n_items   = n_nodes - n_users;      // 25000
    const int N_LAYERS  = 3;
    const int nb        = (n_items + IPB - 1) / IPB;    // 196
    const int chunk     = (half + NCHUNK - 1) / NCHUNK; // 6400

    float* acc = (float*)d_out;

    char* p = (char*)d_ws;
    float* f_cur  = (float*)p;                   p += (size_t)n_total * 4;
    float* f_next = (float*)p;                   p += (size_t)n_total * 4;
    unsigned short* col16 = (unsigned short*)p;  p += (size_t)n_edges * 2;
    unsigned int* stage   = (unsigned int*)p;    p += (size_t)n_edges * 4;
    int*   rp     = (int*)p;                     p += (size_t)(n_nodes + 1) * 4;
    float* dinv   = (float*)p;                   p += (size_t)n_nodes * 4;
    int*   h      = (int*)p;                     p += (size_t)NCHUNK * MAXNB * 4;
    int*   off    = (int*)p;                     p += (size_t)MAXNB * NCHUNK * 4;
    int*   bbase  = (int*)p;                     p += (size_t)(MAXNB + 1) * 4;
    int*   tot    = (int*)p;

    // ---- user rp + user dinv ----
    {
        int ublocks = (n_users + 1 + 255) / 256;
        k_rpu<<<ublocks, 256, 0, stream>>>(rows, rp, n_users, half);
        int dblocks = (n_users + 255) / 256;
        k_dinvu<<<dblocks, 256, 0, stream>>>(rp, dinv, n_users);
    }

    // ---- item half: binned transpose (also produces item rp + item dinv) ----
    {
        int hblocks = (half + 255) / 256;
        k_pack16u<<<hblocks, 256, 0, stream>>>(cols, col16, n_users, half);

        hipMemsetAsync(tot, 0, (size_t)nb * 4, stream);
        k_bhist<<<NCHUNK, 256, 0, stream>>>(rows + half, h, tot, n_users, half, chunk, nb);
        k_bscan<<<1, 256, 0, stream>>>(tot, bbase, half, nb, n_edges);
        k_boff2<<<nb, 256, 0, stream>>>(h, bbase, off, nb, NCHUNK);
        k_bscatter<<<NCHUNK, 256, 0, stream>>>(rows + half, cols + half, off, stage,
                                               n_users, half, chunk, nb, NCHUNK);
        k_brank2<<<nb, 256, 0, stream>>>(bbase, stage, col16, rp, dinv,
                                         n_users, n_items, n_edges);
    }

    // ---- init f_cur = dinv*e0, acc = 0.25*e0 (needs full dinv) ----
    {
        int nvec = n_total / 4;
        int blocks = (nvec + 255) / 256;
        k_init<<<blocks, 256, 0, stream>>>((const float4*)user_embeds,
                                           (const float4*)item_embeds, dinv,
                                           (float4*)f_cur, (float4*)acc,
                                           n_u_elems / 4, nvec);
    }

    // ---- 3 propagation layers; users phase then items phase ----
    {
        int ublocks = (n_users * EMBED + 255) / 256;
        int iblocks = (n_items * EMBED + 255) / 256;
        for (int layer = 0; layer < N_LAYERS; ++layer) {
            int write_f = (layer != N_LAYERS - 1);
            k_spmm<<<ublocks, 256, 0, stream>>>(rp, col16, dinv,
                                                (const float4*)f_cur, (float4*)f_next,
                                                (float4*)acc, 0, n_users, n_users, write_f);
            k_spmm<<<iblocks, 256, 0, stream>>>(rp, col16, dinv,
                                                (const float4*)f_cur, (float4*)f_next,
                                                (float4*)acc, n_users, n_nodes, 0, write_f);
            float* t = f_cur; f_cur = f_next; f_next = t;
        }
    }
}

// Round 9
// 242.409 us; speedup vs baseline: 8.7920x; 1.3614x over previous
//
#include <hip/hip_runtime.h>

#define EMBED 64
#define IPB 128          // items per bucket (shift 7)
#define MAXNB 256        // max buckets (n_items/IPB = 196)
#define NCHUNK 250       // pass-1/2 chunks

// bf16 round-to-nearest-even helpers
__device__ __forceinline__ unsigned int bfr(float x) {
    unsigned int u = __float_as_uint(x);
    return (u + 0x7FFFu + ((u >> 16) & 1u)) >> 16;
}
__device__ __forceinline__ unsigned int pack2(float lo, float hi) {
    return bfr(lo) | (bfr(hi) << 16);
}

// ---------- build kernels ----------

// user row_ptr via binary search on the (sorted) first half of rows
__global__ void k_rpu(const int* __restrict__ rows, int* __restrict__ rp,
                      int n_users, int half) {
    int r = blockIdx.x * blockDim.x + threadIdx.x;
    if (r > n_users) return;
    int lo = 0, hi = half;
    while (lo < hi) {
        int mid = (lo + hi) >> 1;
        if (rows[mid] < r) lo = mid + 1; else hi = mid;
    }
    rp[r] = lo;
}

// user dinv from rp diffs
__global__ void k_dinvu(const int* __restrict__ rp, float* __restrict__ dinv, int n_users) {
    int r = blockIdx.x * blockDim.x + threadIdx.x;
    if (r >= n_users) return;
    int deg = rp[r + 1] - rp[r];
    dinv[r] = (deg > 0) ? (1.0f / sqrtf((float)deg)) : 0.0f;
}

// f_cur(bf16) = dinv * e0 ; acc(f32) = 0.25 * e0 ; 4 dims per thread
__global__ void k_init(const float4* __restrict__ u, const float4* __restrict__ it,
                       const float* __restrict__ dinv,
                       uint2* __restrict__ f, float4* __restrict__ acc,
                       int n_u_vec, int n_total_vec) {
    int idx = blockIdx.x * blockDim.x + threadIdx.x;
    if (idx >= n_total_vec) return;
    float4 v = (idx < n_u_vec) ? u[idx] : it[idx - n_u_vec];
    float dv = dinv[idx >> 4];
    float4 a;  a.x = 0.25f * v.x; a.y = 0.25f * v.y; a.z = 0.25f * v.z; a.w = 0.25f * v.w;
    acc[idx] = a;
    uint2 fv;
    fv.x = pack2(dv * v.x, dv * v.y);
    fv.y = pack2(dv * v.z, dv * v.w);
    f[idx] = fv;
}

// user-half cols -> u16 local item ids, sequential
__global__ void k_pack16u(const int* __restrict__ cols, unsigned short* __restrict__ col16,
                          int n_users, int half) {
    int e = blockIdx.x * blockDim.x + threadIdx.x;
    if (e < half) col16[e] = (unsigned short)(cols[e] - n_users);
}

// ---------- binned transpose (item half) ----------

__global__ void k_bhist(const int* __restrict__ rows_hi, int* __restrict__ h,
                        int* __restrict__ tot, int n_users, int half, int chunk, int nb) {
    __shared__ int lh[MAXNB];
    int b = blockIdx.x;
    int tid = threadIdx.x;
    if (tid < nb) lh[tid] = 0;
    __syncthreads();
    int beg = b * chunk;
    int end = beg + chunk; if (end > half) end = half;
    for (int e = beg + tid; e < end; e += 256)
        atomicAdd(&lh[(rows_hi[e] - n_users) >> 7], 1);
    __syncthreads();
    if (tid < nb) {
        int c = lh[tid];
        h[(size_t)b * nb + tid] = c;
        if (c) atomicAdd(&tot[tid], c);
    }
}

__global__ void k_bscan(const int* __restrict__ tot, int* __restrict__ bbase,
                        int half, int nb, int n_edges) {
    __shared__ int sums[256];
    int tid = threadIdx.x;
    int v = (tid < nb) ? tot[tid] : 0;
    sums[tid] = v;
    __syncthreads();
    for (int o = 1; o < 256; o <<= 1) {
        int t = (tid >= o) ? sums[tid - o] : 0;
        __syncthreads();
        sums[tid] += t;
        __syncthreads();
    }
    if (tid < nb) bbase[tid] = half + sums[tid] - v;
    if (tid == 0) bbase[nb] = n_edges;
}

__global__ void k_boff2(const int* __restrict__ h, const int* __restrict__ bbase,
                        int* __restrict__ off, int nb, int nchunk) {
    __shared__ int sums[256];
    int k = blockIdx.x;
    int tid = threadIdx.x;
    int v = (tid < nchunk) ? h[(size_t)tid * nb + k] : 0;
    sums[tid] = v;
    __syncthreads();
    for (int o = 1; o < 256; o <<= 1) {
        int t = (tid >= o) ? sums[tid - o] : 0;
        __syncthreads();
        sums[tid] += t;
        __syncthreads();
    }
    if (tid < nchunk) off[(size_t)k * nchunk + tid] = bbase[k] + sums[tid] - v;
}

__global__ void k_bscatter(const int* __restrict__ rows_hi, const int* __restrict__ cols_hi,
                           const int* __restrict__ off, unsigned int* __restrict__ stage,
                           int n_users, int half, int chunk, int nb, int nchunk) {
    __shared__ int cur[MAXNB];
    int b = blockIdx.x;
    int tid = threadIdx.x;
    if (tid < nb) cur[tid] = off[(size_t)tid * nchunk + b];
    __syncthreads();
    int beg = b * chunk;
    int end = beg + chunk; if (end > half) end = half;
    for (int e = beg + tid; e < end; e += 256) {
        int item = rows_hi[e] - n_users;
        int user = cols_hi[e];
        int pos = atomicAdd(&cur[item >> 7], 1);
        stage[pos] = (unsigned int)user | ((unsigned int)item << 16);
    }
}

__global__ void k_brank2(const int* __restrict__ bbase, const unsigned int* __restrict__ stage,
                         unsigned short* __restrict__ col16, int* __restrict__ rp,
                         float* __restrict__ dinv, int n_users, int n_items, int n_edges) {
    __shared__ int hist[IPB];
    __shared__ int scanbuf[IPB];
    __shared__ int cur[IPB];
    int k = blockIdx.x;
    int tid = threadIdx.x;
    int first = k * IPB;
    int nit = n_items - first; if (nit > IPB) nit = IPB;
    int beg = bbase[k], end = bbase[k + 1];
    if (tid < IPB) hist[tid] = 0;
    __syncthreads();
    for (int i = beg + tid; i < end; i += 256)
        atomicAdd(&hist[(int)(stage[i] >> 16) - first], 1);
    __syncthreads();
    if (tid < IPB) scanbuf[tid] = hist[tid];
    __syncthreads();
    for (int o = 1; o < IPB; o <<= 1) {
        int t = (tid < IPB && tid >= o) ? scanbuf[tid - o] : 0;
        __syncthreads();
        if (tid < IPB) scanbuf[tid] += t;
        __syncthreads();
    }
    if (tid < nit) {
        int pos = beg + scanbuf[tid] - hist[tid];
        rp[n_users + first + tid] = pos;
        cur[tid] = pos;
        int deg = hist[tid];
        dinv[n_users + first + tid] = (deg > 0) ? (1.0f / sqrtf((float)deg)) : 0.0f;
    }
    if (k == 0 && tid == 0) rp[n_users + n_items] = n_edges;
    __syncthreads();
    for (int i = beg + tid; i < end; i += 256) {
        unsigned int r = stage[i];
        int il = (int)(r >> 16) - first;
        int pos = atomicAdd(&cur[il], 1);
        col16[pos] = (unsigned short)(r & 0xFFFFu);
    }
}

// ---------- SpMM (bf16 table): one wave per row; lane = 8*grp + sub ----------
// grp = edge slot (8), sub = 8-dim slice (uint4 = 8 bf16)
#define ACC8(sv, g) do { \
    sv[0] += __uint_as_float((g).x << 16); sv[1] += __uint_as_float((g).x & 0xFFFF0000u); \
    sv[2] += __uint_as_float((g).y << 16); sv[3] += __uint_as_float((g).y & 0xFFFF0000u); \
    sv[4] += __uint_as_float((g).z << 16); sv[5] += __uint_as_float((g).z & 0xFFFF0000u); \
    sv[6] += __uint_as_float((g).w << 16); sv[7] += __uint_as_float((g).w & 0xFFFF0000u); \
} while (0)

__global__ void k_spmm(const int* __restrict__ rp, const unsigned short* __restrict__ col16,
                       const float* __restrict__ dinv,
                       const uint4* __restrict__ f8, uint4* __restrict__ fnext,
                       float4* __restrict__ acc, int row0, int row1,
                       int gbase, int write_f) {
    int gid = blockIdx.x * blockDim.x + threadIdx.x;
    int row = row0 + (gid >> 6);
    if (row >= row1) return;
    int lane = threadIdx.x & 63;
    int grp  = lane >> 3;   // edge slot 0..7
    int sub  = lane & 7;    // 8-dim slice

    int beg = rp[row], end = rp[row + 1];

    float s[8] = {0.f, 0.f, 0.f, 0.f, 0.f, 0.f, 0.f, 0.f};
    float t[8] = {0.f, 0.f, 0.f, 0.f, 0.f, 0.f, 0.f, 0.f};

    int j = beg + grp;
    for (; j + 8 < end; j += 16) {
        int c0 = col16[j];
        int c1 = col16[j + 8];
        uint4 g0 = f8[(size_t)(c0 + gbase) * 8 + sub];
        uint4 g1 = f8[(size_t)(c1 + gbase) * 8 + sub];
        ACC8(s, g0);
        ACC8(t, g1);
    }
    for (; j < end; j += 8) {
        uint4 g = f8[(size_t)(col16[j] + gbase) * 8 + sub];
        ACC8(s, g);
    }

    #pragma unroll
    for (int d = 0; d < 8; ++d) s[d] += t[d];
    #pragma unroll
    for (int d = 0; d < 8; ++d) {
        s[d] += __shfl_xor(s[d], 8, 64);
        s[d] += __shfl_xor(s[d], 16, 64);
        s[d] += __shfl_xor(s[d], 32, 64);
    }

    if (grp == 0) {
        float dv = dinv[row];
        float q  = 0.25f * dv;
        float d2 = dv * dv;
        int o = row * 16 + sub * 2;          // float4 index into acc
        float4 a0 = acc[o], a1 = acc[o + 1];
        a0.x += q * s[0]; a0.y += q * s[1]; a0.z += q * s[2]; a0.w += q * s[3];
        a1.x += q * s[4]; a1.y += q * s[5]; a1.z += q * s[6]; a1.w += q * s[7];
        acc[o] = a0; acc[o + 1] = a1;
        if (write_f) {
            uint4 fn;
            fn.x = pack2(d2 * s[0], d2 * s[1]);
            fn.y = pack2(d2 * s[2], d2 * s[3]);
            fn.z = pack2(d2 * s[4], d2 * s[5]);
            fn.w = pack2(d2 * s[6], d2 * s[7]);
            fnext[(size_t)row * 8 + sub] = fn;
        }
    }
}

extern "C" void kernel_launch(void* const* d_in, const int* in_sizes, int n_in,
                              void* d_out, int out_size, void* d_ws, size_t ws_size,
                              hipStream_t stream) {
    const float* user_embeds = (const float*)d_in[0];
    const float* item_embeds = (const float*)d_in[1];
    const int*   rows        = (const int*)d_in[3];
    const int*   cols        = (const int*)d_in[4];

    const int n_u_elems = in_sizes[0];            // 50000*64
    const int n_i_elems = in_sizes[1];            // 25000*64
    const int n_total   = n_u_elems + n_i_elems;  // 75000*64
    const int n_edges   = in_sizes[2];            // 3,200,000
    const int half      = n_edges / 2;            // user-sorted half
    const int n_users   = n_u_elems / EMBED;      // 50000
    const int n_nodes   = n_total / EMBED;        // 75000
    const int n_items   = n_nodes - n_users;      // 25000
    const int N_LAYERS  = 3;
    const int nb        = (n_items + IPB - 1) / IPB;    // 196
    const int chunk     = (half + NCHUNK - 1) / NCHUNK; // 6400

    float* acc = (float*)d_out;

    char* p = (char*)d_ws;
    unsigned int* f_cur  = (unsigned int*)p;     p += (size_t)n_total * 2;  // bf16
    unsigned int* f_next = (unsigned int*)p;     p += (size_t)n_total * 2;  // bf16
    unsigned short* col16 = (unsigned short*)p;  p += (size_t)n_edges * 2;
    unsigned int* stage   = (unsigned int*)p;    p += (size_t)n_edges * 4;
    int*   rp     = (int*)p;                     p += (size_t)(n_nodes + 1) * 4;
    float* dinv   = (float*)p;                   p += (size_t)n_nodes * 4;
    int*   h      = (int*)p;                     p += (size_t)NCHUNK * MAXNB * 4;
    int*   off    = (int*)p;                     p += (size_t)MAXNB * NCHUNK * 4;
    int*   bbase  = (int*)p;                     p += (size_t)(MAXNB + 1) * 4;
    int*   tot    = (int*)p;

    // ---- user rp + user dinv ----
    {
        int ublocks = (n_users + 1 + 255) / 256;
        k_rpu<<<ublocks, 256, 0, stream>>>(rows, rp, n_users, half);
        int dblocks = (n_users + 255) / 256;
        k_dinvu<<<dblocks, 256, 0, stream>>>(rp, dinv, n_users);
    }

    // ---- item half: binned transpose (produces item rp + item dinv) ----
    {
        int hblocks = (half + 255) / 256;
        k_pack16u<<<hblocks, 256, 0, stream>>>(cols, col16, n_users, half);

        hipMemsetAsync(tot, 0, (size_t)nb * 4, stream);
        k_bhist<<<NCHUNK, 256, 0, stream>>>(rows + half, h, tot, n_users, half, chunk, nb);
        k_bscan<<<1, 256, 0, stream>>>(tot, bbase, half, nb, n_edges);
        k_boff2<<<nb, 256, 0, stream>>>(h, bbase, off, nb, NCHUNK);
        k_bscatter<<<NCHUNK, 256, 0, stream>>>(rows + half, cols + half, off, stage,
                                               n_users, half, chunk, nb, NCHUNK);
        k_brank2<<<nb, 256, 0, stream>>>(bbase, stage, col16, rp, dinv,
                                         n_users, n_items, n_edges);
    }

    // ---- init f_cur(bf16) = dinv*e0, acc = 0.25*e0 ----
    {
        int nvec = n_total / 4;
        int blocks = (nvec + 255) / 256;
        k_init<<<blocks, 256, 0, stream>>>((const float4*)user_embeds,
                                           (const float4*)item_embeds, dinv,
                                           (uint2*)f_cur, (float4*)acc,
                                           n_u_elems / 4, nvec);
    }

    // ---- 3 propagation layers; users phase then items phase ----
    {
        int ublocks = (n_users * EMBED + 255) / 256;
        int iblocks = (n_items * EMBED + 255) / 256;
        for (int layer = 0; layer < N_LAYERS; ++layer) {
            int write_f = (layer != N_LAYERS - 1);
            k_spmm<<<ublocks, 256, 0, stream>>>(rp, col16, dinv,
                                                (const uint4*)f_cur, (uint4*)f_next,
                                                (float4*)acc, 0, n_users, n_users, write_f);
            k_spmm<<<iblocks, 256, 0, stream>>>(rp, col16, dinv,
                                                (const uint4*)f_cur, (uint4*)f_next,
                                                (float4*)acc, n_users, n_nodes, 0, write_f);
            unsigned int* t = f_cur; f_cur = f_next; f_next = t;
        }
    }
}